// Round 6
// baseline (257.814 us; speedup 1.0000x reference)
//
#include <hip/hip_runtime.h>
#include <math.h>

// DecoderLayer: B=4,N=1,S=256,D=128,H=128,DFF=512, fp32 end-to-end.
// Round-6: 3 dispatches. Scores never materialized.
//  1. proj3: x -> xw -> {qa,kb} ; enc -> kv2w -> {kb2,ka2}  (chained via LDS)
//  2. attn_fused<self>: per-block 8 q-rows: pairwise BOTH terms (transpose term
//     computed directly: relu(qa[k]+kb[q]) == relu(At[k]+Bq[q]), same form as
//     cross) k-tiled through LDS w/ register prefetch -> softmax -> AV ->
//     outproj+res+LN -> out1, then out1 -> q2w -> {qa2,qb2} chained in LDS.
//  3. attn_fused<cross>: same pairwise structure (t1=relu(qa2+kb2),
//     t2=relu(qb2+ka2)) -> ... -> out2 rows kept in LDS -> ffn1+relu+ffn2+
//     res+LN3 -> out.  out2/sbuf never hit global.
// b2 dropped (softmax shift invariance). RES_RATIO=1 -> plain residual add.
// Round-3 lesson: grid.sync ~40us on MI355X -> multi-dispatch, no coop.

#define LN_EPS 1e-6f
#define NEGV  (-1e9f)

constexpr int B = 4, S = 256, D = 128, H = 128, DFF = 512;
constexpr int R = B * S;   // 1024 rows (N=1)
constexpr int LDW = H + 4; // padded LDS row stride

struct P {
    const float *x, *enc, *com_mask, *dec_mask;
    const float *W1q, *W1k, *b1, *W2;
    const float *Ww1, *bw1, *Wd1, *bd1;
    const float *Ww2, *bw2, *Wd2, *bd2;
    const float *Wf1, *bf1, *Wf2, *bf2;
    const float *ln1g, *ln1b, *ln2g, *ln2b, *ln3g, *ln3b;
    float *out;
    float *xw, *qa, *kb, *kv2w, *kb2, *ka2, *qa2, *qb2, *out1;
};

// ---- in-LDS 8-row x 128 matmul helper: returns row lr, float4-col c4 ----
__device__ __forceinline__ float4 mm8(const float* AshS, const float* W,
                                      const float* bias, int lr, int c4)
{
    const float4* W4 = (const float4*)W;
    float4 acc = bias ? ((const float4*)bias)[c4] : make_float4(0.f, 0.f, 0.f, 0.f);
    #pragma unroll 8
    for (int k = 0; k < 128; ++k) {
        const float a = AshS[lr * 128 + k];
        const float4 w = W4[k * 32 + c4];
        acc.x = fmaf(a, w.x, acc.x); acc.y = fmaf(a, w.y, acc.y);
        acc.z = fmaf(a, w.z, acc.z); acc.w = fmaf(a, w.w, acc.w);
    }
    return acc;
}

// ================= 1: chained projections, grid (R/8, 2) =================
__global__ __launch_bounds__(256) void proj3_kernel(P p)
{
    const int g = blockIdx.y, tid = threadIdx.x;
    const int r0 = blockIdx.x * 8;
    const int lr = tid >> 5, c4 = tid & 31;
    __shared__ float Ash[8 * 128];
    __shared__ float Pw[8 * 128];

    const float* A    = g ? p.enc  : p.x;
    const float* Wp   = g ? p.Ww2  : p.Ww1;
    const float* bp   = g ? p.bw2  : p.bw1;
    float*       o_w  = g ? p.kv2w : p.xw;
    const float* Wsec = g ? p.W1k  : p.W1q;  // kb2 | qa
    const float* bsec = g ? nullptr: p.b1;
    float*       o_s  = g ? p.kb2  : p.qa;
    const float* Wthr = g ? p.W1q  : p.W1k;  // ka2 | kb
    float*       o_t  = g ? p.ka2  : p.kb;

    ((float4*)Ash)[tid] = ((const float4*)(A + (size_t)r0 * 128))[tid];
    __syncthreads();
    {
        const float4 w = mm8(Ash, Wp, bp, lr, c4);
        ((float4*)(Pw + lr * 128))[c4] = w;
        ((float4*)o_w)[(size_t)(r0 + lr) * 32 + c4] = w;
    }
    __syncthreads();
    {
        const float4 q = mm8(Pw, Wsec, bsec, lr, c4);
        ((float4*)o_s)[(size_t)(r0 + lr) * 32 + c4] = q;
        const float4 k = mm8(Pw, Wthr, nullptr, lr, c4);
        ((float4*)o_t)[(size_t)(r0 + lr) * 32 + c4] = k;
    }
}

// ================= 2/3: fused attention (+ffn for cross) =================
// smem carve (floats):
//  W2s 0..128 | Aq 128..1184 | Bq 1184..2240 | s8 2240..4288 |
//  rowS 4288..5312 | aoS 5312..6336 | Kt 6336..10560 | At 10560..14784
//  ffn aliases (cross, after pairwise dead): h1p 6336(+8192), hid 6336(+4096),
//  p2 10432(+4096)
template<bool CROSS>
__global__ __launch_bounds__(256) void attn_fused(P p)
{
    __shared__ __align__(16) float smem[14784];  // 59.1 KB
    float* W2s  = smem;
    float* Aq   = smem + 128;
    float* Bq   = smem + 1184;
    float* s8   = smem + 2240;
    float* rowS = smem + 4288;
    float* aoS  = smem + 5312;
    float* Kt   = smem + 6336;
    float* At   = smem + 10560;

    const int tid = threadIdx.x;
    const int r0 = blockIdx.x * 8, bS = r0 & ~(S - 1);

    const float* Aq_src = CROSS ? p.qa2 : p.qa;   // q-side, term1
    const float* Bq_src = CROSS ? p.qb2 : p.kb;   // q-side, term2
    const float* Kt_src = CROSS ? p.kb2 : p.kb;   // k-side, term1
    const float* At_src = CROSS ? p.ka2 : p.qa;   // k-side, term2
    const float* mask   = CROSS ? p.dec_mask : p.com_mask;
    const float* V      = CROSS ? p.kv2w : p.xw;
    const float* Wd     = CROSS ? p.Wd2 : p.Wd1;
    const float* bd     = CROSS ? p.bd2 : p.bd1;
    const float* res    = CROSS ? p.out1 : p.x;
    const float* lg     = CROSS ? p.ln2g : p.ln1g;
    const float* lb     = CROSS ? p.ln2b : p.ln1b;

    // ---- setup: W2, q-side rows ----
    if (tid < 32) ((float4*)W2s)[tid] = ((const float4*)p.W2)[tid];
    {
        const int r = tid >> 5, c4 = tid & 31;
        ((float4*)(Aq + r * LDW))[c4] = ((const float4*)(Aq_src + (size_t)(r0 + r) * H))[c4];
        ((float4*)(Bq + r * LDW))[c4] = ((const float4*)(Bq_src + (size_t)(r0 + r) * H))[c4];
    }

    // ---- pairwise over 8 k-tiles of 32 rows, register-prefetch dbuf ----
    float4 pK[4], pA[4];
    {
        #pragma unroll
        for (int j = 0; j < 4; ++j) {
            const int i = tid + j * 256, r = i >> 5, c4 = i & 31;
            pK[j] = ((const float4*)(Kt_src + (size_t)(bS + r) * H))[c4];
            pA[j] = ((const float4*)(At_src + (size_t)(bS + r) * H))[c4];
        }
    }
    const int q = tid >> 5, kk = tid & 31;
    const float* aq = Aq + q * LDW;
    const float* bq = Bq + q * LDW;
    const float* kt = Kt + kk * LDW;
    const float* at = At + kk * LDW;

    for (int t = 0; t < 8; ++t) {
        __syncthreads();   // previous tile's readers done (also covers setup)
        #pragma unroll
        for (int j = 0; j < 4; ++j) {
            const int i = tid + j * 256, r = i >> 5, c4 = i & 31;
            ((float4*)(Kt + r * LDW))[c4] = pK[j];
            ((float4*)(At + r * LDW))[c4] = pA[j];
        }
        __syncthreads();
        if (t < 7) {
            #pragma unroll
            for (int j = 0; j < 4; ++j) {
                const int i = tid + j * 256, r = i >> 5, c4 = i & 31;
                pK[j] = ((const float4*)(Kt_src + (size_t)(bS + (t + 1) * 32 + r) * H))[c4];
                pA[j] = ((const float4*)(At_src + (size_t)(bS + (t + 1) * 32 + r) * H))[c4];
            }
        }
        float4 accA = make_float4(0.f, 0.f, 0.f, 0.f);
        float4 accB = make_float4(0.f, 0.f, 0.f, 0.f);
        #pragma unroll 8
        for (int h = 0; h < H; h += 4) {
            const float4 w  = *(const float4*)(W2s + h);
            const float4 a  = *(const float4*)(aq + h);
            const float4 k4 = *(const float4*)(kt + h);
            const float4 b4 = *(const float4*)(bq + h);
            const float4 a4 = *(const float4*)(at + h);
            accA.x = fmaf(fmaxf(a.x + k4.x, 0.f), w.x, accA.x);
            accA.y = fmaf(fmaxf(a.y + k4.y, 0.f), w.y, accA.y);
            accA.z = fmaf(fmaxf(a.z + k4.z, 0.f), w.z, accA.z);
            accA.w = fmaf(fmaxf(a.w + k4.w, 0.f), w.w, accA.w);
            accB.x = fmaf(fmaxf(b4.x + a4.x, 0.f), w.x, accB.x);
            accB.y = fmaf(fmaxf(b4.y + a4.y, 0.f), w.y, accB.y);
            accB.z = fmaf(fmaxf(b4.z + a4.z, 0.f), w.z, accB.z);
            accB.w = fmaf(fmaxf(b4.w + a4.w, 0.f), w.w, accB.w);
        }
        s8[q * 256 + t * 32 + kk] = (accA.x + accA.y + accA.z + accA.w)
                                  + (accB.x + accB.y + accB.z + accB.w);
    }
    __syncthreads();

    // ---- softmax (mask applied here) ----
    {
        const int g = tid >> 5, c = tid & 31;
        float* rowp = s8 + g * 256;
        const float* mrow = mask + (size_t)(r0 + g) * S;
        float m = -INFINITY;
        for (int k = c; k < 256; k += 32) {
            const float v = rowp[k] + mrow[k] * NEGV;
            rowp[k] = v;
            m = fmaxf(m, v);
        }
        for (int o = 16; o; o >>= 1) m = fmaxf(m, __shfl_xor(m, o, 32));
        float s = 0.f;
        for (int k = c; k < 256; k += 32) { const float e = __expf(rowp[k] - m); rowp[k] = e; s += e; }
        for (int o = 16; o; o >>= 1) s += __shfl_xor(s, o, 32);
        const float rinv = 1.f / s;
        for (int k = c; k < 256; k += 32) rowp[k] *= rinv;
    }
    __syncthreads();

    // ---- AV ----
    const int lr = tid >> 5, c4 = tid & 31;
    {
        const float4* V4 = (const float4*)(V + (size_t)bS * D);
        float4 acc = make_float4(0.f, 0.f, 0.f, 0.f);
        #pragma unroll 8
        for (int k = 0; k < 256; ++k) {
            const float a = s8[lr * 256 + k];
            const float4 v = V4[k * 32 + c4];
            acc.x = fmaf(a, v.x, acc.x); acc.y = fmaf(a, v.y, acc.y);
            acc.z = fmaf(a, v.z, acc.z); acc.w = fmaf(a, v.w, acc.w);
        }
        ((float4*)(aoS + lr * 128))[c4] = acc;
    }
    __syncthreads();

    // ---- outproj + residual + LN ----
    {
        float4 o = mm8(aoS, Wd, bd, lr, c4);
        const float4 r4 = ((const float4*)(res + (size_t)(r0 + lr) * 128))[c4];
        const float x0 = o.x + r4.x, x1 = o.y + r4.y, x2 = o.z + r4.z, x3 = o.w + r4.w;
        float s  = x0 + x1 + x2 + x3;
        float s2 = x0 * x0 + x1 * x1 + x2 * x2 + x3 * x3;
        for (int of = 16; of; of >>= 1) { s += __shfl_xor(s, of, 32); s2 += __shfl_xor(s2, of, 32); }
        const float m = s * (1.f / 128), var = s2 * (1.f / 128) - m * m;
        const float rs = rsqrtf(var + LN_EPS);
        const float4 gv = ((const float4*)lg)[c4], bv = ((const float4*)lb)[c4];
        float4 o4;
        o4.x = (x0 - m) * rs * gv.x + bv.x; o4.y = (x1 - m) * rs * gv.y + bv.y;
        o4.z = (x2 - m) * rs * gv.z + bv.z; o4.w = (x3 - m) * rs * gv.w + bv.w;
        ((float4*)(rowS + lr * 128))[c4] = o4;
        if (!CROSS) ((float4*)p.out1)[(size_t)(r0 + lr) * 32 + c4] = o4;
    }
    __syncthreads();

    if (!CROSS) {
        // ---- q-side chain: q2w = out1@Ww2+bw2 -> qa2/qb2 ----
        const float4 w = mm8(rowS, p.Ww2, p.bw2, lr, c4);
        __syncthreads();
        ((float4*)(aoS + lr * 128))[c4] = w;
        __syncthreads();
        const float4 qv = mm8(aoS, p.W1q, p.b1, lr, c4);
        ((float4*)p.qa2)[(size_t)(r0 + lr) * 32 + c4] = qv;
        const float4 kv = mm8(aoS, p.W1k, p.b1, lr, c4);
        ((float4*)p.qb2)[(size_t)(r0 + lr) * 32 + c4] = kv;
    } else {
        // ---- ffn on the 8 out2 rows in rowS; out2 never hits global ----
        float* h1p = smem + 6336;   // [2][8][512] partials
        float* hid = smem + 6336;   // [8][512] after combine
        float* p2  = smem + 10432;  // [4][8][128] ffn2 partials

        {   // ffn1: c = tid&127 (float4 col of 512), kh = tid>>7 (k-half)
            const int c = tid & 127, kh = tid >> 7;
            const float4* Wf1_4 = (const float4*)p.Wf1;
            float4 a0 = make_float4(0.f,0.f,0.f,0.f), a1 = a0, a2 = a0, a3 = a0,
                   a4 = a0, a5 = a0, a6 = a0, a7 = a0;
            const int kbase = kh * 64;
            #pragma unroll 8
            for (int k = 0; k < 64; ++k) {
                const int kkk = kbase + k;
                const float4 w = Wf1_4[kkk * 128 + c];
                const float s0 = rowS[kkk],       s1 = rowS[128 + kkk];
                const float s2 = rowS[256 + kkk], s3 = rowS[384 + kkk];
                const float s4 = rowS[512 + kkk], s5 = rowS[640 + kkk];
                const float s6 = rowS[768 + kkk], s7 = rowS[896 + kkk];
                a0.x=fmaf(s0,w.x,a0.x); a0.y=fmaf(s0,w.y,a0.y); a0.z=fmaf(s0,w.z,a0.z); a0.w=fmaf(s0,w.w,a0.w);
                a1.x=fmaf(s1,w.x,a1.x); a1.y=fmaf(s1,w.y,a1.y); a1.z=fmaf(s1,w.z,a1.z); a1.w=fmaf(s1,w.w,a1.w);
                a2.x=fmaf(s2,w.x,a2.x); a2.y=fmaf(s2,w.y,a2.y); a2.z=fmaf(s2,w.z,a2.z); a2.w=fmaf(s2,w.w,a2.w);
                a3.x=fmaf(s3,w.x,a3.x); a3.y=fmaf(s3,w.y,a3.y); a3.z=fmaf(s3,w.z,a3.z); a3.w=fmaf(s3,w.w,a3.w);
                a4.x=fmaf(s4,w.x,a4.x); a4.y=fmaf(s4,w.y,a4.y); a4.z=fmaf(s4,w.z,a4.z); a4.w=fmaf(s4,w.w,a4.w);
                a5.x=fmaf(s5,w.x,a5.x); a5.y=fmaf(s5,w.y,a5.y); a5.z=fmaf(s5,w.z,a5.z); a5.w=fmaf(s5,w.w,a5.w);
                a6.x=fmaf(s6,w.x,a6.x); a6.y=fmaf(s6,w.y,a6.y); a6.z=fmaf(s6,w.z,a6.z); a6.w=fmaf(s6,w.w,a6.w);
                a7.x=fmaf(s7,w.x,a7.x); a7.y=fmaf(s7,w.y,a7.y); a7.z=fmaf(s7,w.z,a7.z); a7.w=fmaf(s7,w.w,a7.w);
            }
            float4* h4 = (float4*)h1p;
            const int base = kh * 1024;
            h4[base + 0*128 + c] = a0; h4[base + 1*128 + c] = a1;
            h4[base + 2*128 + c] = a2; h4[base + 3*128 + c] = a3;
            h4[base + 4*128 + c] = a4; h4[base + 5*128 + c] = a5;
            h4[base + 6*128 + c] = a6; h4[base + 7*128 + c] = a7;
        }
        __syncthreads();
        for (int i = tid; i < 4096; i += 256) {
            hid[i] = fmaxf(h1p[i] + h1p[4096 + i] + p.bf1[i & 511], 0.f);
        }
        __syncthreads();
        {   // ffn2: c4f = tid&31, kg = (tid>>5)&3 (k-quarter), rh = tid>>7 (row-half)
            const int c4f = tid & 31, kg = (tid >> 5) & 3, rh = tid >> 7;
            const float4* Wf2_4 = (const float4*)p.Wf2;
            float4 a0 = make_float4(0.f,0.f,0.f,0.f), a1 = a0, a2 = a0, a3 = a0;
            const int kbase = kg * 128;
            const float* h0 = hid + (rh * 4 + 0) * 512 + kbase;
            const float* h1 = hid + (rh * 4 + 1) * 512 + kbase;
            const float* h2 = hid + (rh * 4 + 2) * 512 + kbase;
            const float* h3 = hid + (rh * 4 + 3) * 512 + kbase;
            #pragma unroll 8
            for (int k = 0; k < 128; ++k) {
                const float4 w = Wf2_4[(kbase + k) * 32 + c4f];
                const float s0 = h0[k], s1 = h1[k], s2 = h2[k], s3 = h3[k];
                a0.x=fmaf(s0,w.x,a0.x); a0.y=fmaf(s0,w.y,a0.y); a0.z=fmaf(s0,w.z,a0.z); a0.w=fmaf(s0,w.w,a0.w);
                a1.x=fmaf(s1,w.x,a1.x); a1.y=fmaf(s1,w.y,a1.y); a1.z=fmaf(s1,w.z,a1.z); a1.w=fmaf(s1,w.w,a1.w);
                a2.x=fmaf(s2,w.x,a2.x); a2.y=fmaf(s2,w.y,a2.y); a2.z=fmaf(s2,w.z,a2.z); a2.w=fmaf(s2,w.w,a2.w);
                a3.x=fmaf(s3,w.x,a3.x); a3.y=fmaf(s3,w.y,a3.y); a3.z=fmaf(s3,w.z,a3.z); a3.w=fmaf(s3,w.w,a3.w);
            }
            float4* p4 = (float4*)p2;
            p4[kg * 256 + (rh * 4 + 0) * 32 + c4f] = a0;
            p4[kg * 256 + (rh * 4 + 1) * 32 + c4f] = a1;
            p4[kg * 256 + (rh * 4 + 2) * 32 + c4f] = a2;
            p4[kg * 256 + (rh * 4 + 3) * 32 + c4f] = a3;
        }
        __syncthreads();
        {   // reduce 4 k-partials + bias + residual + LN3 -> out
            const float4* p4 = (const float4*)p2;
            float4 sum = ((const float4*)p.bf2)[c4];
            #pragma unroll
            for (int kg = 0; kg < 4; ++kg) {
                const float4 v = p4[kg * 256 + lr * 32 + c4];
                sum.x += v.x; sum.y += v.y; sum.z += v.z; sum.w += v.w;
            }
            const float4 r4 = ((const float4*)(rowS + lr * 128))[c4];
            const float x0 = sum.x + r4.x, x1 = sum.y + r4.y;
            const float x2 = sum.z + r4.z, x3 = sum.w + r4.w;
            float s  = x0 + x1 + x2 + x3;
            float s2 = x0 * x0 + x1 * x1 + x2 * x2 + x3 * x3;
            for (int of = 16; of; of >>= 1) { s += __shfl_xor(s, of, 32); s2 += __shfl_xor(s2, of, 32); }
            const float m = s * (1.f / 128), var = s2 * (1.f / 128) - m * m;
            const float rs = rsqrtf(var + LN_EPS);
            const float4 gv = ((const float4*)p.ln3g)[c4], bv = ((const float4*)p.ln3b)[c4];
            float4 o4;
            o4.x = (x0 - m) * rs * gv.x + bv.x; o4.y = (x1 - m) * rs * gv.y + bv.y;
            o4.z = (x2 - m) * rs * gv.z + bv.z; o4.w = (x3 - m) * rs * gv.w + bv.w;
            ((float4*)p.out)[(size_t)(r0 + lr) * 32 + c4] = o4;
        }
    }
}

extern "C" void kernel_launch(void* const* d_in, const int* in_sizes, int n_in,
                              void* d_out, int out_size, void* d_ws, size_t ws_size,
                              hipStream_t stream) {
    (void)in_sizes; (void)n_in; (void)out_size; (void)ws_size;
    P p;
    p.x        = (const float*)d_in[0];
    p.enc      = (const float*)d_in[1];
    p.com_mask = (const float*)d_in[2];
    p.dec_mask = (const float*)d_in[3];
    p.W1q = (const float*)d_in[4];
    p.W1k = (const float*)d_in[5];
    p.b1  = (const float*)d_in[6];
    p.W2  = (const float*)d_in[7];
    // d_in[8] = b2: per-row constant -> dropped (softmax shift invariance)
    p.Ww1 = (const float*)d_in[9];
    p.bw1 = (const float*)d_in[10];
    p.Wd1 = (const float*)d_in[11];
    p.bd1 = (const float*)d_in[12];
    p.Ww2 = (const float*)d_in[13];
    p.bw2 = (const float*)d_in[14];
    p.Wd2 = (const float*)d_in[15];
    p.bd2 = (const float*)d_in[16];
    p.Wf1 = (const float*)d_in[17];
    p.bf1 = (const float*)d_in[18];
    p.Wf2 = (const float*)d_in[19];
    p.bf2 = (const float*)d_in[20];
    p.ln1g = (const float*)d_in[21];
    p.ln1b = (const float*)d_in[22];
    p.ln2g = (const float*)d_in[23];
    p.ln2b = (const float*)d_in[24];
    p.ln3g = (const float*)d_in[25];
    p.ln3b = (const float*)d_in[26];
    p.out  = (float*)d_out;

    float* ws = (float*)d_ws;
    const size_t RD = (size_t)R * D;  // 131072
    p.xw   = ws;
    p.qa   = p.xw   + RD;
    p.kb   = p.qa   + RD;
    p.kv2w = p.kb   + RD;
    p.kb2  = p.kv2w + RD;
    p.ka2  = p.kb2  + RD;
    p.qa2  = p.ka2  + RD;
    p.qb2  = p.qa2  + RD;
    p.out1 = p.qb2  + RD;

    proj3_kernel<<<dim3(R / 8, 2), 256, 0, stream>>>(p);
    attn_fused<false><<<R / 8, 256, 0, stream>>>(p);
    attn_fused<true><<<R / 8, 256, 0, stream>>>(p);
}

// Round 7
// 214.786 us; speedup vs baseline: 1.2003x; 1.2003x over previous
//
#include <hip/hip_runtime.h>
#include <math.h>

// DecoderLayer: B=4,N=1,S=256,D=128,H=128,DFF=512, fp32 end-to-end.
// Round-7: revert to round-5 structure (199us), 5 dispatches.
// Round-6 lesson: in-kernel pairwise (fat blocks, 128-grid, LDS-staged k-tiles)
// is latency-bound (75us, VALUBusy 8%, occ 4.8%) -> keep pairwise as separate
// 32x32-tile kernels at 256 blocks. Safe fusion only: ffn folded into
// attn_tail2 epilogue (out2 rows already in LDS; out2 never hits global).
//  1. proj3: x -> xw -> {qa,kb} ; enc -> kv2w -> {kb2,ka2}  (chained via LDS)
//  2. pairwise_self (sym term = transpose, read in stage 3)
//  3. attn_tail<SYM,QPROJ>: softmax(+sym)+AV+outproj+res+LN -> out1,
//     then out1 -> q2w -> {qa2,qb2} chained in LDS
//  4. pairwise_cross2 (both symmetric terms, two-phase LDS)
//  5. attn_tail<FFN>: softmax+AV+outproj+res+LN (out2 in LDS) ->
//     ffn1+relu+ffn2+res+LN3 -> out  (register-tiled ffn, weights once/block)
// b2 dropped (softmax shift invariance). RES_RATIO=1 -> plain residual add.
// Round-3 lesson: grid.sync ~40us on MI355X -> no cooperative path.

#define LN_EPS 1e-6f
#define NEGV  (-1e9f)

constexpr int B = 4, S = 256, D = 128, H = 128, DFF = 512;
constexpr int R = B * S;   // 1024 rows (N=1)
constexpr int LDW = H + 4; // padded pairwise LDS stride (16B-aligned rows)

struct P {
    const float *x, *enc, *com_mask, *dec_mask;
    const float *W1q, *W1k, *b1, *W2;
    const float *Ww1, *bw1, *Wd1, *bd1;
    const float *Ww2, *bw2, *Wd2, *bd2;
    const float *Wf1, *bf1, *Wf2, *bf2;
    const float *ln1g, *ln1b, *ln2g, *ln2b, *ln3g, *ln3b;
    float *out;
    float *xw, *qa, *kb, *kv2w, *kb2, *ka2, *qa2, *qb2;
    float *sbuf, *sbuf2, *out1;
};

// ---- in-LDS 8-row x 128 matmul helper: returns row lr, float4-col c4 ----
__device__ __forceinline__ float4 mm8(const float* AshS, const float* W,
                                      const float* bias, int lr, int c4)
{
    const float4* W4 = (const float4*)W;
    float4 acc = bias ? ((const float4*)bias)[c4] : make_float4(0.f, 0.f, 0.f, 0.f);
    #pragma unroll 8
    for (int k = 0; k < 128; ++k) {
        const float a = AshS[lr * 128 + k];
        const float4 w = W4[k * 32 + c4];
        acc.x = fmaf(a, w.x, acc.x); acc.y = fmaf(a, w.y, acc.y);
        acc.z = fmaf(a, w.z, acc.z); acc.w = fmaf(a, w.w, acc.w);
    }
    return acc;
}

// ================= 1: chained projections, grid (R/8, 2) =================
__global__ __launch_bounds__(256) void proj3_kernel(P p)
{
    const int g = blockIdx.y, tid = threadIdx.x;
    const int r0 = blockIdx.x * 8;
    const int lr = tid >> 5, c4 = tid & 31;
    __shared__ float Ash[8 * 128];
    __shared__ float Pw[8 * 128];

    const float* A    = g ? p.enc  : p.x;
    const float* Wp   = g ? p.Ww2  : p.Ww1;
    const float* bp   = g ? p.bw2  : p.bw1;
    float*       o_w  = g ? p.kv2w : p.xw;
    const float* Wsec = g ? p.W1k  : p.W1q;  // kb2 | qa
    const float* bsec = g ? nullptr: p.b1;
    float*       o_s  = g ? p.kb2  : p.qa;
    const float* Wthr = g ? p.W1q  : p.W1k;  // ka2 | kb
    float*       o_t  = g ? p.ka2  : p.kb;

    ((float4*)Ash)[tid] = ((const float4*)(A + (size_t)r0 * 128))[tid];
    __syncthreads();
    {
        const float4 w = mm8(Ash, Wp, bp, lr, c4);
        ((float4*)(Pw + lr * 128))[c4] = w;
        ((float4*)o_w)[(size_t)(r0 + lr) * 32 + c4] = w;
    }
    __syncthreads();
    {
        const float4 q = mm8(Pw, Wsec, bsec, lr, c4);
        ((float4*)o_s)[(size_t)(r0 + lr) * 32 + c4] = q;
        const float4 k = mm8(Pw, Wthr, nullptr, lr, c4);
        ((float4*)o_t)[(size_t)(r0 + lr) * 32 + c4] = k;
    }
}

// ---- pairwise accumulate helper (float4 over h) ----
#define PW_STEP(AP0, AP1, BP0, BP1)                                            \
    {                                                                          \
        const float4 w  = *(const float4*)(W2s + h);                           \
        const float4 a0 = *(const float4*)((AP0) + h);                         \
        const float4 a1 = *(const float4*)((AP1) + h);                         \
        const float4 b0 = *(const float4*)((BP0) + h);                         \
        const float4 b1 = *(const float4*)((BP1) + h);                         \
        acc00 = fmaf(fmaxf(a0.x+b0.x,0.f),w.x,acc00); acc00 = fmaf(fmaxf(a0.y+b0.y,0.f),w.y,acc00); \
        acc00 = fmaf(fmaxf(a0.z+b0.z,0.f),w.z,acc00); acc00 = fmaf(fmaxf(a0.w+b0.w,0.f),w.w,acc00); \
        acc01 = fmaf(fmaxf(a0.x+b1.x,0.f),w.x,acc01); acc01 = fmaf(fmaxf(a0.y+b1.y,0.f),w.y,acc01); \
        acc01 = fmaf(fmaxf(a0.z+b1.z,0.f),w.z,acc01); acc01 = fmaf(fmaxf(a0.w+b1.w,0.f),w.w,acc01); \
        acc10 = fmaf(fmaxf(a1.x+b0.x,0.f),w.x,acc10); acc10 = fmaf(fmaxf(a1.y+b0.y,0.f),w.y,acc10); \
        acc10 = fmaf(fmaxf(a1.z+b0.z,0.f),w.z,acc10); acc10 = fmaf(fmaxf(a1.w+b0.w,0.f),w.w,acc10); \
        acc11 = fmaf(fmaxf(a1.x+b1.x,0.f),w.x,acc11); acc11 = fmaf(fmaxf(a1.y+b1.y,0.f),w.y,acc11); \
        acc11 = fmaf(fmaxf(a1.z+b1.z,0.f),w.z,acc11); acc11 = fmaf(fmaxf(a1.w+b1.w,0.f),w.w,acc11); \
    }

// ================= 2: self pairwise (single term) =================
__global__ __launch_bounds__(256) void pairwise_self_kernel(P p)
{
    __shared__ __align__(16) float As[32 * LDW];
    __shared__ __align__(16) float Bs[32 * LDW];
    __shared__ __align__(16) float W2s[H];
    const int b = blockIdx.z, q0 = blockIdx.y * 32, k0 = blockIdx.x * 32;
    const int tid = threadIdx.x, bS = b * S;
    for (int i = tid; i < 32 * (H / 4); i += 256) {
        const int r = i >> 5, c4 = i & 31;
        ((float4*)(As + r * LDW))[c4] = ((const float4*)(p.qa + (size_t)(bS + q0 + r) * H))[c4];
        ((float4*)(Bs + r * LDW))[c4] = ((const float4*)(p.kb + (size_t)(bS + k0 + r) * H))[c4];
    }
    if (tid < H / 4) ((float4*)W2s)[tid] = ((const float4*)p.W2)[tid];
    __syncthreads();
    const int tx = tid & 15, ty = tid >> 4;
    const float* A0 = As + (2 * ty) * LDW; const float* A1 = A0 + LDW;
    const float* B0 = Bs + (2 * tx) * LDW; const float* B1 = B0 + LDW;
    float acc00 = 0.f, acc01 = 0.f, acc10 = 0.f, acc11 = 0.f;
    #pragma unroll 4
    for (int h = 0; h < H; h += 4) PW_STEP(A0, A1, B0, B1);
    const size_t base = (size_t)(bS + q0 + 2 * ty) * S + (k0 + 2 * tx);
    *(float2*)(p.sbuf + base)     = make_float2(acc00, acc01);
    *(float2*)(p.sbuf + base + S) = make_float2(acc10, acc11);
}

// ================= 4: cross pairwise, both symmetric terms =================
__global__ __launch_bounds__(256) void pairwise_cross2_kernel(P p)
{
    __shared__ __align__(16) float As[32 * LDW];
    __shared__ __align__(16) float Bs[32 * LDW];
    __shared__ __align__(16) float W2s[H];
    const int b = blockIdx.z, q0 = blockIdx.y * 32, k0 = blockIdx.x * 32;
    const int tid = threadIdx.x, bS = b * S;
    const int tx = tid & 15, ty = tid >> 4;
    const float* A0 = As + (2 * ty) * LDW; const float* A1 = A0 + LDW;
    const float* B0 = Bs + (2 * tx) * LDW; const float* B1 = B0 + LDW;
    float acc00 = 0.f, acc01 = 0.f, acc10 = 0.f, acc11 = 0.f;

    for (int i = tid; i < 32 * (H / 4); i += 256) {
        const int r = i >> 5, c4 = i & 31;
        ((float4*)(As + r * LDW))[c4] = ((const float4*)(p.qa2 + (size_t)(bS + q0 + r) * H))[c4];
        ((float4*)(Bs + r * LDW))[c4] = ((const float4*)(p.kb2 + (size_t)(bS + k0 + r) * H))[c4];
    }
    if (tid < H / 4) ((float4*)W2s)[tid] = ((const float4*)p.W2)[tid];
    __syncthreads();
    #pragma unroll 4
    for (int h = 0; h < H; h += 4) PW_STEP(A0, A1, B0, B1);
    __syncthreads();
    for (int i = tid; i < 32 * (H / 4); i += 256) {
        const int r = i >> 5, c4 = i & 31;
        ((float4*)(As + r * LDW))[c4] = ((const float4*)(p.qb2 + (size_t)(bS + q0 + r) * H))[c4];
        ((float4*)(Bs + r * LDW))[c4] = ((const float4*)(p.ka2 + (size_t)(bS + k0 + r) * H))[c4];
    }
    __syncthreads();
    #pragma unroll 4
    for (int h = 0; h < H; h += 4) PW_STEP(A0, A1, B0, B1);
    const size_t base = (size_t)(bS + q0 + 2 * ty) * S + (k0 + 2 * tx);
    *(float2*)(p.sbuf2 + base)     = make_float2(acc00, acc01);
    *(float2*)(p.sbuf2 + base + S) = make_float2(acc10, acc11);
}

// ======= 3/5: softmax(+sym)+AV+outproj+res+LN (+q-chain | +ffn) =======
// smem carve (floats): rowS [0,1024) | s8 [1024,3072) | aoS [3072,4096)
// ffn aliases (dead s8/aoS): h1p/hid [1024,9216) | p2 [9216,13312)
template<bool SYM, bool QPROJ, bool FFN>
__global__ __launch_bounds__(256) void attn_tail_kernel(P p)
{
    __shared__ __align__(16) float smem[FFN ? 13312 : 4096];
    float* rowS = smem;
    float* s8   = smem + 1024;
    float* aoS  = smem + 3072;

    const float* Sin  = SYM ? p.sbuf : p.sbuf2;
    const float* mask = SYM ? p.com_mask : p.dec_mask;
    const float* V    = SYM ? p.xw : p.kv2w;
    const float* Wd   = SYM ? p.Wd1 : p.Wd2;
    const float* bd   = SYM ? p.bd1 : p.bd2;
    const float* res  = SYM ? p.x : p.out1;
    const float* lg   = SYM ? p.ln1g : p.ln2g;
    const float* lb   = SYM ? p.ln1b : p.ln2b;

    const int tid = threadIdx.x;
    const int r0 = blockIdx.x * 8, b = r0 >> 8, bS = b * S;

    for (int i = tid; i < 8 * 256; i += 256) {
        const int r = i >> 8, k = i & 255;
        const int row = r0 + r, q = row & 255;
        float l = Sin[(size_t)row * S + k];
        if (SYM) l += Sin[(size_t)(bS + k) * S + q];
        l += mask[(size_t)row * S + k] * NEGV;
        s8[i] = l;
    }
    __syncthreads();
    {
        const int g = tid >> 5, c = tid & 31;
        float* rowp = s8 + g * 256;
        float m = -INFINITY;
        for (int k = c; k < 256; k += 32) m = fmaxf(m, rowp[k]);
        for (int o = 16; o; o >>= 1) m = fmaxf(m, __shfl_xor(m, o, 32));
        float s = 0.f;
        for (int k = c; k < 256; k += 32) { const float e = __expf(rowp[k] - m); rowp[k] = e; s += e; }
        for (int o = 16; o; o >>= 1) s += __shfl_xor(s, o, 32);
        const float rinv = 1.f / s;
        for (int k = c; k < 256; k += 32) rowp[k] *= rinv;
    }
    __syncthreads();
    const int lr = tid >> 5, c4 = tid & 31;
    {
        const float4* V4 = (const float4*)(V + (size_t)bS * D);
        float4 acc = make_float4(0.f, 0.f, 0.f, 0.f);
        #pragma unroll 8
        for (int k = 0; k < 256; ++k) {
            const float a = s8[lr * 256 + k];
            const float4 v = V4[k * 32 + c4];
            acc.x = fmaf(a, v.x, acc.x); acc.y = fmaf(a, v.y, acc.y);
            acc.z = fmaf(a, v.z, acc.z); acc.w = fmaf(a, v.w, acc.w);
        }
        ((float4*)(aoS + lr * 128))[c4] = acc;
    }
    __syncthreads();
    {
        float4 o = mm8(aoS, Wd, bd, lr, c4);
        const float4 r4 = ((const float4*)(res + (size_t)(r0 + lr) * 128))[c4];
        const float x0 = o.x + r4.x, x1 = o.y + r4.y, x2 = o.z + r4.z, x3 = o.w + r4.w;
        float s  = x0 + x1 + x2 + x3;
        float s2 = x0 * x0 + x1 * x1 + x2 * x2 + x3 * x3;
        for (int of = 16; of; of >>= 1) { s += __shfl_xor(s, of, 32); s2 += __shfl_xor(s2, of, 32); }
        const float m = s * (1.f / 128), var = s2 * (1.f / 128) - m * m;
        const float rs = rsqrtf(var + LN_EPS);
        const float4 gv = ((const float4*)lg)[c4], bv = ((const float4*)lb)[c4];
        float4 o4;
        o4.x = (x0 - m) * rs * gv.x + bv.x; o4.y = (x1 - m) * rs * gv.y + bv.y;
        o4.z = (x2 - m) * rs * gv.z + bv.z; o4.w = (x3 - m) * rs * gv.w + bv.w;
        ((float4*)(rowS + lr * 128))[c4] = o4;
        if (SYM) ((float4*)p.out1)[(size_t)(r0 + lr) * 32 + c4] = o4;
    }
    __syncthreads();

    if (QPROJ) {
        // q2w = out1@Ww2+bw2 (LDS), then qa2 = q2w@W1q+b1, qb2 = q2w@W1k+b1
        const float4 w = mm8(rowS, p.Ww2, p.bw2, lr, c4);
        __syncthreads();
        ((float4*)(aoS + lr * 128))[c4] = w;
        __syncthreads();
        const float4 qv = mm8(aoS, p.W1q, p.b1, lr, c4);
        ((float4*)p.qa2)[(size_t)(r0 + lr) * 32 + c4] = qv;
        const float4 kv = mm8(aoS, p.W1k, p.b1, lr, c4);
        ((float4*)p.qb2)[(size_t)(r0 + lr) * 32 + c4] = kv;
    }

    if (FFN) {
        // ffn on the 8 out2 rows in rowS; out2 never hits global.
        float* h1p = smem + 1024;   // [2][8][512] partials (aliases s8/aoS, dead)
        float* hid = smem + 1024;   // [8][512] after combine
        float* p2  = smem + 9216;   // [4][8][128] ffn2 partials

        {   // ffn1: c = tid&127 (float4 col of 512), kh = tid>>7 (k-half)
            const int c = tid & 127, kh = tid >> 7;
            const float4* Wf1_4 = (const float4*)p.Wf1;
            float4 a0 = make_float4(0.f,0.f,0.f,0.f), a1 = a0, a2 = a0, a3 = a0,
                   a4 = a0, a5 = a0, a6 = a0, a7 = a0;
            const int kbase = kh * 64;
            #pragma unroll 8
            for (int k = 0; k < 64; ++k) {
                const int kk = kbase + k;
                const float4 w = Wf1_4[kk * 128 + c];
                const float s0 = rowS[kk],       s1 = rowS[128 + kk];
                const float s2 = rowS[256 + kk], s3 = rowS[384 + kk];
                const float s4 = rowS[512 + kk], s5 = rowS[640 + kk];
                const float s6 = rowS[768 + kk], s7 = rowS[896 + kk];
                a0.x=fmaf(s0,w.x,a0.x); a0.y=fmaf(s0,w.y,a0.y); a0.z=fmaf(s0,w.z,a0.z); a0.w=fmaf(s0,w.w,a0.w);
                a1.x=fmaf(s1,w.x,a1.x); a1.y=fmaf(s1,w.y,a1.y); a1.z=fmaf(s1,w.z,a1.z); a1.w=fmaf(s1,w.w,a1.w);
                a2.x=fmaf(s2,w.x,a2.x); a2.y=fmaf(s2,w.y,a2.y); a2.z=fmaf(s2,w.z,a2.z); a2.w=fmaf(s2,w.w,a2.w);
                a3.x=fmaf(s3,w.x,a3.x); a3.y=fmaf(s3,w.y,a3.y); a3.z=fmaf(s3,w.z,a3.z); a3.w=fmaf(s3,w.w,a3.w);
                a4.x=fmaf(s4,w.x,a4.x); a4.y=fmaf(s4,w.y,a4.y); a4.z=fmaf(s4,w.z,a4.z); a4.w=fmaf(s4,w.w,a4.w);
                a5.x=fmaf(s5,w.x,a5.x); a5.y=fmaf(s5,w.y,a5.y); a5.z=fmaf(s5,w.z,a5.z); a5.w=fmaf(s5,w.w,a5.w);
                a6.x=fmaf(s6,w.x,a6.x); a6.y=fmaf(s6,w.y,a6.y); a6.z=fmaf(s6,w.z,a6.z); a6.w=fmaf(s6,w.w,a6.w);
                a7.x=fmaf(s7,w.x,a7.x); a7.y=fmaf(s7,w.y,a7.y); a7.z=fmaf(s7,w.z,a7.z); a7.w=fmaf(s7,w.w,a7.w);
            }
            float4* h4 = (float4*)h1p;
            const int base = kh * 1024;
            h4[base + 0*128 + c] = a0; h4[base + 1*128 + c] = a1;
            h4[base + 2*128 + c] = a2; h4[base + 3*128 + c] = a3;
            h4[base + 4*128 + c] = a4; h4[base + 5*128 + c] = a5;
            h4[base + 6*128 + c] = a6; h4[base + 7*128 + c] = a7;
        }
        __syncthreads();
        for (int i = tid; i < 4096; i += 256) {
            hid[i] = fmaxf(h1p[i] + h1p[4096 + i] + p.bf1[i & 511], 0.f);
        }
        __syncthreads();
        {   // ffn2: c4f = tid&31, kg = (tid>>5)&3 (k-quarter), rh = tid>>7
            const int c4f = tid & 31, kg = (tid >> 5) & 3, rh = tid >> 7;
            const float4* Wf2_4 = (const float4*)p.Wf2;
            float4 a0 = make_float4(0.f,0.f,0.f,0.f), a1 = a0, a2 = a0, a3 = a0;
            const int kbase = kg * 128;
            const float* h0 = hid + (rh * 4 + 0) * 512 + kbase;
            const float* h1 = hid + (rh * 4 + 1) * 512 + kbase;
            const float* h2 = hid + (rh * 4 + 2) * 512 + kbase;
            const float* h3 = hid + (rh * 4 + 3) * 512 + kbase;
            #pragma unroll 8
            for (int k = 0; k < 128; ++k) {
                const float4 w = Wf2_4[(kbase + k) * 32 + c4f];
                const float s0 = h0[k], s1 = h1[k], s2 = h2[k], s3 = h3[k];
                a0.x=fmaf(s0,w.x,a0.x); a0.y=fmaf(s0,w.y,a0.y); a0.z=fmaf(s0,w.z,a0.z); a0.w=fmaf(s0,w.w,a0.w);
                a1.x=fmaf(s1,w.x,a1.x); a1.y=fmaf(s1,w.y,a1.y); a1.z=fmaf(s1,w.z,a1.z); a1.w=fmaf(s1,w.w,a1.w);
                a2.x=fmaf(s2,w.x,a2.x); a2.y=fmaf(s2,w.y,a2.y); a2.z=fmaf(s2,w.z,a2.z); a2.w=fmaf(s2,w.w,a2.w);
                a3.x=fmaf(s3,w.x,a3.x); a3.y=fmaf(s3,w.y,a3.y); a3.z=fmaf(s3,w.z,a3.z); a3.w=fmaf(s3,w.w,a3.w);
            }
            float4* p4 = (float4*)p2;
            p4[kg * 256 + (rh * 4 + 0) * 32 + c4f] = a0;
            p4[kg * 256 + (rh * 4 + 1) * 32 + c4f] = a1;
            p4[kg * 256 + (rh * 4 + 2) * 32 + c4f] = a2;
            p4[kg * 256 + (rh * 4 + 3) * 32 + c4f] = a3;
        }
        __syncthreads();
        {   // reduce 4 k-partials + bias + residual + LN3 -> out
            const float4* p4 = (const float4*)p2;
            float4 sum = ((const float4*)p.bf2)[c4];
            #pragma unroll
            for (int kg = 0; kg < 4; ++kg) {
                const float4 v = p4[kg * 256 + lr * 32 + c4];
                sum.x += v.x; sum.y += v.y; sum.z += v.z; sum.w += v.w;
            }
            const float4 r4 = ((const float4*)(rowS + lr * 128))[c4];
            const float x0 = sum.x + r4.x, x1 = sum.y + r4.y;
            const float x2 = sum.z + r4.z, x3 = sum.w + r4.w;
            float s  = x0 + x1 + x2 + x3;
            float s2 = x0 * x0 + x1 * x1 + x2 * x2 + x3 * x3;
            for (int of = 16; of; of >>= 1) { s += __shfl_xor(s, of, 32); s2 += __shfl_xor(s2, of, 32); }
            const float m = s * (1.f / 128), var = s2 * (1.f / 128) - m * m;
            const float rs = rsqrtf(var + LN_EPS);
            const float4 gv = ((const float4*)p.ln3g)[c4], bv = ((const float4*)p.ln3b)[c4];
            float4 o4;
            o4.x = (x0 - m) * rs * gv.x + bv.x; o4.y = (x1 - m) * rs * gv.y + bv.y;
            o4.z = (x2 - m) * rs * gv.z + bv.z; o4.w = (x3 - m) * rs * gv.w + bv.w;
            ((float4*)p.out)[(size_t)(r0 + lr) * 32 + c4] = o4;
        }
    }
}

extern "C" void kernel_launch(void* const* d_in, const int* in_sizes, int n_in,
                              void* d_out, int out_size, void* d_ws, size_t ws_size,
                              hipStream_t stream) {
    (void)in_sizes; (void)n_in; (void)out_size; (void)ws_size;
    P p;
    p.x        = (const float*)d_in[0];
    p.enc      = (const float*)d_in[1];
    p.com_mask = (const float*)d_in[2];
    p.dec_mask = (const float*)d_in[3];
    p.W1q = (const float*)d_in[4];
    p.W1k = (const float*)d_in[5];
    p.b1  = (const float*)d_in[6];
    p.W2  = (const float*)d_in[7];
    // d_in[8] = b2: per-row constant -> dropped (softmax shift invariance)
    p.Ww1 = (const float*)d_in[9];
    p.bw1 = (const float*)d_in[10];
    p.Wd1 = (const float*)d_in[11];
    p.bd1 = (const float*)d_in[12];
    p.Ww2 = (const float*)d_in[13];
    p.bw2 = (const float*)d_in[14];
    p.Wd2 = (const float*)d_in[15];
    p.bd2 = (const float*)d_in[16];
    p.Wf1 = (const float*)d_in[17];
    p.bf1 = (const float*)d_in[18];
    p.Wf2 = (const float*)d_in[19];
    p.bf2 = (const float*)d_in[20];
    p.ln1g = (const float*)d_in[21];
    p.ln1b = (const float*)d_in[22];
    p.ln2g = (const float*)d_in[23];
    p.ln2b = (const float*)d_in[24];
    p.ln3g = (const float*)d_in[25];
    p.ln3b = (const float*)d_in[26];
    p.out  = (float*)d_out;

    float* ws = (float*)d_ws;
    const size_t RD  = (size_t)R * D;      // 131072
    const size_t SSz = (size_t)B * S * S;  // 262144
    p.xw    = ws;
    p.qa    = p.xw    + RD;
    p.kb    = p.qa    + RD;
    p.kv2w  = p.kb    + RD;
    p.kb2   = p.kv2w  + RD;
    p.ka2   = p.kb2   + RD;
    p.qa2   = p.ka2   + RD;
    p.qb2   = p.qa2   + RD;
    p.sbuf  = p.qb2   + RD;    // SSz
    p.sbuf2 = p.sbuf  + SSz;   // SSz
    p.out1  = p.sbuf2 + SSz;

    proj3_kernel<<<dim3(R / 8, 2), 256, 0, stream>>>(p);
    pairwise_self_kernel<<<dim3(8, 8, 4), 256, 0, stream>>>(p);
    attn_tail_kernel<true, true, false><<<R / 8, 256, 0, stream>>>(p);
    pairwise_cross2_kernel<<<dim3(8, 8, 4), 256, 0, stream>>>(p);
    attn_tail_kernel<false, false, true><<<R / 8, 256, 0, stream>>>(p);
}

// Round 8
// 183.502 us; speedup vs baseline: 1.4050x; 1.1705x over previous
//
#include <hip/hip_runtime.h>
#include <math.h>

// DecoderLayer: B=4,N=1,S=256,D=128,H=128,DFF=512, fp32 end-to-end.
// Round-8: 5 dispatches; attn_tail rebuilt at 4 rows/block x 256 blocks.
// R6/R7 lesson: fusion must never shrink the grid. R7's 128-block fused tail
// ran 52-62us (occ 5%); the same FFN math at 256 blocks (R5) was ~10us.
//  1. proj3: x -> xw -> {qa,kb} ; enc -> kv2w -> {kb2,ka2}  (chained via LDS)
//  2. pairwise_self (sym term = transpose, read in stage 3)
//  3. attn_tail<SYM,QPROJ>: 4 rows/block: softmax(+sym)+AV(k-split)+outproj
//     (k-split)+res+LN -> out1, then out1 -> q2w -> {qa2,qb2} in LDS
//  4. pairwise_cross2 (both symmetric terms, two-phase LDS)
//  5. attn_tail<FFN>: same attention tail -> out2 rows in LDS ->
//     ffn1+relu+ffn2+res+LN3 -> out (register-tiled, weights once/block)
// b2 dropped (softmax shift invariance). RES_RATIO=1 -> plain residual add.
// R3 lesson: grid.sync ~40us on MI355X -> no cooperative path.

#define LN_EPS 1e-6f
#define NEGV  (-1e9f)

constexpr int B = 4, S = 256, D = 128, H = 128, DFF = 512;
constexpr int R = B * S;   // 1024 rows (N=1)
constexpr int LDW = H + 4; // padded pairwise LDS stride (16B-aligned rows)

struct P {
    const float *x, *enc, *com_mask, *dec_mask;
    const float *W1q, *W1k, *b1, *W2;
    const float *Ww1, *bw1, *Wd1, *bd1;
    const float *Ww2, *bw2, *Wd2, *bd2;
    const float *Wf1, *bf1, *Wf2, *bf2;
    const float *ln1g, *ln1b, *ln2g, *ln2b, *ln3g, *ln3b;
    float *out;
    float *xw, *qa, *kb, *kv2w, *kb2, *ka2, *qa2, *qb2;
    float *sbuf, *sbuf2, *out1;
};

// ---- in-LDS 8-row x 128 matmul helper (proj3): row lr, float4-col c4 ----
__device__ __forceinline__ float4 mm8(const float* AshS, const float* W,
                                      const float* bias, int lr, int c4)
{
    const float4* W4 = (const float4*)W;
    float4 acc = bias ? ((const float4*)bias)[c4] : make_float4(0.f, 0.f, 0.f, 0.f);
    #pragma unroll 8
    for (int k = 0; k < 128; ++k) {
        const float a = AshS[lr * 128 + k];
        const float4 w = W4[k * 32 + c4];
        acc.x = fmaf(a, w.x, acc.x); acc.y = fmaf(a, w.y, acc.y);
        acc.z = fmaf(a, w.z, acc.z); acc.w = fmaf(a, w.w, acc.w);
    }
    return acc;
}

// ================= 1: chained projections, grid (R/8, 2) =================
__global__ __launch_bounds__(256) void proj3_kernel(P p)
{
    const int g = blockIdx.y, tid = threadIdx.x;
    const int r0 = blockIdx.x * 8;
    const int lr = tid >> 5, c4 = tid & 31;
    __shared__ float Ash[8 * 128];
    __shared__ float Pw[8 * 128];

    const float* A    = g ? p.enc  : p.x;
    const float* Wp   = g ? p.Ww2  : p.Ww1;
    const float* bp   = g ? p.bw2  : p.bw1;
    float*       o_w  = g ? p.kv2w : p.xw;
    const float* Wsec = g ? p.W1k  : p.W1q;  // kb2 | qa
    const float* bsec = g ? nullptr: p.b1;
    float*       o_s  = g ? p.kb2  : p.qa;
    const float* Wthr = g ? p.W1q  : p.W1k;  // ka2 | kb
    float*       o_t  = g ? p.ka2  : p.kb;

    ((float4*)Ash)[tid] = ((const float4*)(A + (size_t)r0 * 128))[tid];
    __syncthreads();
    {
        const float4 w = mm8(Ash, Wp, bp, lr, c4);
        ((float4*)(Pw + lr * 128))[c4] = w;
        ((float4*)o_w)[(size_t)(r0 + lr) * 32 + c4] = w;
    }
    __syncthreads();
    {
        const float4 q = mm8(Pw, Wsec, bsec, lr, c4);
        ((float4*)o_s)[(size_t)(r0 + lr) * 32 + c4] = q;
        const float4 k = mm8(Pw, Wthr, nullptr, lr, c4);
        ((float4*)o_t)[(size_t)(r0 + lr) * 32 + c4] = k;
    }
}

// ---- pairwise accumulate helper (float4 over h) ----
#define PW_STEP(AP0, AP1, BP0, BP1)                                            \
    {                                                                          \
        const float4 w  = *(const float4*)(W2s + h);                           \
        const float4 a0 = *(const float4*)((AP0) + h);                         \
        const float4 a1 = *(const float4*)((AP1) + h);                         \
        const float4 b0 = *(const float4*)((BP0) + h);                         \
        const float4 b1 = *(const float4*)((BP1) + h);                         \
        acc00 = fmaf(fmaxf(a0.x+b0.x,0.f),w.x,acc00); acc00 = fmaf(fmaxf(a0.y+b0.y,0.f),w.y,acc00); \
        acc00 = fmaf(fmaxf(a0.z+b0.z,0.f),w.z,acc00); acc00 = fmaf(fmaxf(a0.w+b0.w,0.f),w.w,acc00); \
        acc01 = fmaf(fmaxf(a0.x+b1.x,0.f),w.x,acc01); acc01 = fmaf(fmaxf(a0.y+b1.y,0.f),w.y,acc01); \
        acc01 = fmaf(fmaxf(a0.z+b1.z,0.f),w.z,acc01); acc01 = fmaf(fmaxf(a0.w+b1.w,0.f),w.w,acc01); \
        acc10 = fmaf(fmaxf(a1.x+b0.x,0.f),w.x,acc10); acc10 = fmaf(fmaxf(a1.y+b0.y,0.f),w.y,acc10); \
        acc10 = fmaf(fmaxf(a1.z+b0.z,0.f),w.z,acc10); acc10 = fmaf(fmaxf(a1.w+b0.w,0.f),w.w,acc10); \
        acc11 = fmaf(fmaxf(a1.x+b1.x,0.f),w.x,acc11); acc11 = fmaf(fmaxf(a1.y+b1.y,0.f),w.y,acc11); \
        acc11 = fmaf(fmaxf(a1.z+b1.z,0.f),w.z,acc11); acc11 = fmaf(fmaxf(a1.w+b1.w,0.f),w.w,acc11); \
    }

// ================= 2: self pairwise (single term) =================
__global__ __launch_bounds__(256) void pairwise_self_kernel(P p)
{
    __shared__ __align__(16) float As[32 * LDW];
    __shared__ __align__(16) float Bs[32 * LDW];
    __shared__ __align__(16) float W2s[H];
    const int b = blockIdx.z, q0 = blockIdx.y * 32, k0 = blockIdx.x * 32;
    const int tid = threadIdx.x, bS = b * S;
    for (int i = tid; i < 32 * (H / 4); i += 256) {
        const int r = i >> 5, c4 = i & 31;
        ((float4*)(As + r * LDW))[c4] = ((const float4*)(p.qa + (size_t)(bS + q0 + r) * H))[c4];
        ((float4*)(Bs + r * LDW))[c4] = ((const float4*)(p.kb + (size_t)(bS + k0 + r) * H))[c4];
    }
    if (tid < H / 4) ((float4*)W2s)[tid] = ((const float4*)p.W2)[tid];
    __syncthreads();
    const int tx = tid & 15, ty = tid >> 4;
    const float* A0 = As + (2 * ty) * LDW; const float* A1 = A0 + LDW;
    const float* B0 = Bs + (2 * tx) * LDW; const float* B1 = B0 + LDW;
    float acc00 = 0.f, acc01 = 0.f, acc10 = 0.f, acc11 = 0.f;
    #pragma unroll 4
    for (int h = 0; h < H; h += 4) PW_STEP(A0, A1, B0, B1);
    const size_t base = (size_t)(bS + q0 + 2 * ty) * S + (k0 + 2 * tx);
    *(float2*)(p.sbuf + base)     = make_float2(acc00, acc01);
    *(float2*)(p.sbuf + base + S) = make_float2(acc10, acc11);
}

// ================= 4: cross pairwise, both symmetric terms =================
__global__ __launch_bounds__(256) void pairwise_cross2_kernel(P p)
{
    __shared__ __align__(16) float As[32 * LDW];
    __shared__ __align__(16) float Bs[32 * LDW];
    __shared__ __align__(16) float W2s[H];
    const int b = blockIdx.z, q0 = blockIdx.y * 32, k0 = blockIdx.x * 32;
    const int tid = threadIdx.x, bS = b * S;
    const int tx = tid & 15, ty = tid >> 4;
    const float* A0 = As + (2 * ty) * LDW; const float* A1 = A0 + LDW;
    const float* B0 = Bs + (2 * tx) * LDW; const float* B1 = B0 + LDW;
    float acc00 = 0.f, acc01 = 0.f, acc10 = 0.f, acc11 = 0.f;

    for (int i = tid; i < 32 * (H / 4); i += 256) {
        const int r = i >> 5, c4 = i & 31;
        ((float4*)(As + r * LDW))[c4] = ((const float4*)(p.qa2 + (size_t)(bS + q0 + r) * H))[c4];
        ((float4*)(Bs + r * LDW))[c4] = ((const float4*)(p.kb2 + (size_t)(bS + k0 + r) * H))[c4];
    }
    if (tid < H / 4) ((float4*)W2s)[tid] = ((const float4*)p.W2)[tid];
    __syncthreads();
    #pragma unroll 4
    for (int h = 0; h < H; h += 4) PW_STEP(A0, A1, B0, B1);
    __syncthreads();
    for (int i = tid; i < 32 * (H / 4); i += 256) {
        const int r = i >> 5, c4 = i & 31;
        ((float4*)(As + r * LDW))[c4] = ((const float4*)(p.qb2 + (size_t)(bS + q0 + r) * H))[c4];
        ((float4*)(Bs + r * LDW))[c4] = ((const float4*)(p.ka2 + (size_t)(bS + k0 + r) * H))[c4];
    }
    __syncthreads();
    #pragma unroll 4
    for (int h = 0; h < H; h += 4) PW_STEP(A0, A1, B0, B1);
    const size_t base = (size_t)(bS + q0 + 2 * ty) * S + (k0 + 2 * tx);
    *(float2*)(p.sbuf2 + base)     = make_float2(acc00, acc01);
    *(float2*)(p.sbuf2 + base + S) = make_float2(acc10, acc11);
}

// ======= 3/5: 4-row attn tail: softmax(+sym)+AV+outproj+res+LN =======
// grid = R/4 = 256 blocks (full machine). 256 threads = 4 waves; wave r owns
// row r. k-split partials through LDS keep per-thread chains short.
// smem carve (floats): rowS [0,512) | s8 [512,1536) | avp [1536,2560) |
//   aoS [2560,3072) | pp [3072,4096)
// QPROJ aliases: qpp = s8, q2wS = avp.
// FFN aliases (all attn scratch dead): hidP [512,4608) | part [4608,8704)
template<bool SYM, bool QPROJ, bool FFN>
__global__ __launch_bounds__(256) void attn_tail_kernel(P p)
{
    __shared__ __align__(16) float smem[FFN ? 8704 : 4096];
    float* rowS = smem;
    float* s8   = smem + 512;
    float* avp  = smem + 1536;
    float* aoS  = smem + 2560;
    float* pp   = smem + 3072;

    const float* Sin  = SYM ? p.sbuf : p.sbuf2;
    const float* mask = SYM ? p.com_mask : p.dec_mask;
    const float* V    = SYM ? p.xw : p.kv2w;
    const float* Wd   = SYM ? p.Wd1 : p.Wd2;
    const float* bd   = SYM ? p.bd1 : p.bd2;
    const float* res  = SYM ? p.x : p.out1;
    const float* lg   = SYM ? p.ln1g : p.ln2g;
    const float* lb   = SYM ? p.ln1b : p.ln2b;

    const int tid = threadIdx.x;
    const int r0 = blockIdx.x * 4, b = r0 >> 8, bS = b * S;

    // ---- scores + mask (+sym transpose) into s8[4][256] ----
    for (int i = tid; i < 4 * 256; i += 256) {
        const int r = i >> 8, k = i & 255;
        const int row = r0 + r, q = row & 255;
        float l = Sin[(size_t)row * S + k];
        if (SYM) l += Sin[(size_t)(bS + k) * S + q];
        l += mask[(size_t)row * S + k] * NEGV;
        s8[i] = l;
    }
    __syncthreads();

    // ---- softmax: wave g owns row g; 64-lane shuffles ----
    {
        const int g = tid >> 6, c = tid & 63;
        float* rowp = s8 + g * 256;
        float m = -INFINITY;
        #pragma unroll
        for (int k = c; k < 256; k += 64) m = fmaxf(m, rowp[k]);
        for (int o = 32; o; o >>= 1) m = fmaxf(m, __shfl_xor(m, o, 64));
        float s = 0.f;
        #pragma unroll
        for (int k = c; k < 256; k += 64) { const float e = __expf(rowp[k] - m); rowp[k] = e; s += e; }
        for (int o = 32; o; o >>= 1) s += __shfl_xor(s, o, 64);
        const float rinv = 1.f / s;
        #pragma unroll
        for (int k = c; k < 256; k += 64) rowp[k] *= rinv;
    }
    __syncthreads();

    // ---- AV, k-split by 2: wave r, half-wave kh ----
    {
        const int r = tid >> 6, t = tid & 63, c4 = t & 31, kh = t >> 5;
        const float4* V4 = (const float4*)(V + (size_t)bS * D);
        const float* sp = s8 + r * 256 + kh * 128;
        float4 acc = make_float4(0.f, 0.f, 0.f, 0.f);
        #pragma unroll 8
        for (int k = 0; k < 128; ++k) {
            const float a = sp[k];
            const float4 v = V4[(kh * 128 + k) * 32 + c4];
            acc.x = fmaf(a, v.x, acc.x); acc.y = fmaf(a, v.y, acc.y);
            acc.z = fmaf(a, v.z, acc.z); acc.w = fmaf(a, v.w, acc.w);
        }
        ((float4*)avp)[(r * 2 + kh) * 32 + c4] = acc;
    }
    __syncthreads();
    if (tid < 128) {
        const int r = tid >> 5, c4 = tid & 31;
        const float4 a = ((const float4*)avp)[(r * 2 + 0) * 32 + c4];
        const float4 bq = ((const float4*)avp)[(r * 2 + 1) * 32 + c4];
        ((float4*)aoS)[r * 32 + c4] = make_float4(a.x + bq.x, a.y + bq.y, a.z + bq.z, a.w + bq.w);
    }
    __syncthreads();

    // ---- outproj, k-split by 2 ----
    {
        const int kh = tid >> 7, unit = tid & 127, r = unit >> 5, c4 = unit & 31;
        const float4* W4 = (const float4*)Wd;
        const float* ap = aoS + r * 128 + kh * 64;
        float4 acc = make_float4(0.f, 0.f, 0.f, 0.f);
        #pragma unroll 8
        for (int k = 0; k < 64; ++k) {
            const float a = ap[k];
            const float4 w = W4[(kh * 64 + k) * 32 + c4];
            acc.x = fmaf(a, w.x, acc.x); acc.y = fmaf(a, w.y, acc.y);
            acc.z = fmaf(a, w.z, acc.z); acc.w = fmaf(a, w.w, acc.w);
        }
        ((float4*)pp)[kh * 128 + unit] = acc;
    }
    __syncthreads();

    // ---- combine + bias + residual + LN -> rowS (and out1 if SYM) ----
    if (tid < 128) {
        const int r = tid >> 5, c4 = tid & 31;
        const float4 p0 = ((const float4*)pp)[tid];
        const float4 p1 = ((const float4*)pp)[128 + tid];
        const float4 bv0 = ((const float4*)bd)[c4];
        const float4 r4 = ((const float4*)(res + (size_t)(r0 + r) * 128))[c4];
        const float x0 = p0.x + p1.x + bv0.x + r4.x;
        const float x1 = p0.y + p1.y + bv0.y + r4.y;
        const float x2 = p0.z + p1.z + bv0.z + r4.z;
        const float x3 = p0.w + p1.w + bv0.w + r4.w;
        float s  = x0 + x1 + x2 + x3;
        float s2 = x0 * x0 + x1 * x1 + x2 * x2 + x3 * x3;
        for (int o = 16; o; o >>= 1) { s += __shfl_xor(s, o, 32); s2 += __shfl_xor(s2, o, 32); }
        const float m = s * (1.f / 128), var = s2 * (1.f / 128) - m * m;
        const float rs = rsqrtf(var + LN_EPS);
        const float4 gv = ((const float4*)lg)[c4], bv = ((const float4*)lb)[c4];
        float4 o4;
        o4.x = (x0 - m) * rs * gv.x + bv.x; o4.y = (x1 - m) * rs * gv.y + bv.y;
        o4.z = (x2 - m) * rs * gv.z + bv.z; o4.w = (x3 - m) * rs * gv.w + bv.w;
        ((float4*)rowS)[r * 32 + c4] = o4;
        if (SYM) ((float4*)p.out1)[(size_t)(r0 + r) * 32 + c4] = o4;
    }
    __syncthreads();

    if (QPROJ) {
        float* qpp  = s8;   // [2][512]
        float* q2wS = avp;  // [4][128]
        {   // q2w partials, k-split by 2
            const int kh = tid >> 7, unit = tid & 127, r = unit >> 5, c4 = unit & 31;
            const float4* W4 = (const float4*)p.Ww2;
            const float* ap = rowS + r * 128 + kh * 64;
            float4 acc = make_float4(0.f, 0.f, 0.f, 0.f);
            #pragma unroll 8
            for (int k = 0; k < 64; ++k) {
                const float a = ap[k];
                const float4 w = W4[(kh * 64 + k) * 32 + c4];
                acc.x = fmaf(a, w.x, acc.x); acc.y = fmaf(a, w.y, acc.y);
                acc.z = fmaf(a, w.z, acc.z); acc.w = fmaf(a, w.w, acc.w);
            }
            ((float4*)qpp)[kh * 128 + unit] = acc;
        }
        __syncthreads();
        if (tid < 128) {
            const int c4 = tid & 31;
            const float4 p0 = ((const float4*)qpp)[tid];
            const float4 p1 = ((const float4*)qpp)[128 + tid];
            const float4 bw = ((const float4*)p.bw2)[c4];
            ((float4*)q2wS)[tid] = make_float4(p0.x + p1.x + bw.x, p0.y + p1.y + bw.y,
                                               p0.z + p1.z + bw.z, p0.w + p1.w + bw.w);
        }
        __syncthreads();
        {   // qa2 = q2w@W1q + b1 ; qb2 = q2w@W1k + b1  (256 units exactly)
            const int which = tid >> 7, unit = tid & 127, r = unit >> 5, c4 = unit & 31;
            const float4* W4 = (const float4*)(which ? p.W1k : p.W1q);
            float* oq = which ? p.qb2 : p.qa2;
            const float* ap = q2wS + r * 128;
            float4 acc = ((const float4*)p.b1)[c4];
            #pragma unroll 8
            for (int k = 0; k < 128; ++k) {
                const float a = ap[k];
                const float4 w = W4[k * 32 + c4];
                acc.x = fmaf(a, w.x, acc.x); acc.y = fmaf(a, w.y, acc.y);
                acc.z = fmaf(a, w.z, acc.z); acc.w = fmaf(a, w.w, acc.w);
            }
            ((float4*)oq)[(size_t)(r0 + r) * 32 + c4] = acc;
        }
    }

    if (FFN) {
        float* hidP = smem + 512;   // [2][4][512] partials; [0,2048) becomes hidden
        float* part = smem + 4608;  // [8][4][128]
        {   // ffn1: float4-col c of 128, k-half kh; 4-row register accs
            const int c = tid & 127, kh = tid >> 7;
            const float4* Wf1_4 = (const float4*)p.Wf1;
            float4 a0 = make_float4(0.f,0.f,0.f,0.f), a1 = a0, a2 = a0, a3 = a0;
            const int kbase = kh * 64;
            #pragma unroll 8
            for (int k = 0; k < 64; ++k) {
                const int kk = kbase + k;
                const float4 w = Wf1_4[kk * 128 + c];
                const float s0 = rowS[kk],       s1 = rowS[128 + kk];
                const float s2 = rowS[256 + kk], s3 = rowS[384 + kk];
                a0.x=fmaf(s0,w.x,a0.x); a0.y=fmaf(s0,w.y,a0.y); a0.z=fmaf(s0,w.z,a0.z); a0.w=fmaf(s0,w.w,a0.w);
                a1.x=fmaf(s1,w.x,a1.x); a1.y=fmaf(s1,w.y,a1.y); a1.z=fmaf(s1,w.z,a1.z); a1.w=fmaf(s1,w.w,a1.w);
                a2.x=fmaf(s2,w.x,a2.x); a2.y=fmaf(s2,w.y,a2.y); a2.z=fmaf(s2,w.z,a2.z); a2.w=fmaf(s2,w.w,a2.w);
                a3.x=fmaf(s3,w.x,a3.x); a3.y=fmaf(s3,w.y,a3.y); a3.z=fmaf(s3,w.z,a3.z); a3.w=fmaf(s3,w.w,a3.w);
            }
            float4* h4 = (float4*)hidP;
            const int base = kh * 512;
            h4[base + 0*128 + c] = a0; h4[base + 1*128 + c] = a1;
            h4[base + 2*128 + c] = a2; h4[base + 3*128 + c] = a3;
        }
        __syncthreads();
        for (int i = tid; i < 2048; i += 256) {
            hidP[i] = fmaxf(hidP[i] + hidP[2048 + i] + p.bf1[i & 511], 0.f);
        }
        __syncthreads();
        {   // ffn2: c4f of 32, k-group kg (8 x 64); 4-row register accs
            const int c4f = tid & 31, kg = tid >> 5;
            const float4* Wf2_4 = (const float4*)p.Wf2;
            float4 a0 = make_float4(0.f,0.f,0.f,0.f), a1 = a0, a2 = a0, a3 = a0;
            const int kbase = kg * 64;
            const float* h0 = hidP + 0 * 512 + kbase;
            const float* h1 = hidP + 1 * 512 + kbase;
            const float* h2 = hidP + 2 * 512 + kbase;
            const float* h3 = hidP + 3 * 512 + kbase;
            #pragma unroll 8
            for (int k = 0; k < 64; ++k) {
                const float4 w = Wf2_4[(kbase + k) * 32 + c4f];
                const float s0 = h0[k], s1 = h1[k], s2 = h2[k], s3 = h3[k];
                a0.x=fmaf(s0,w.x,a0.x); a0.y=fmaf(s0,w.y,a0.y); a0.z=fmaf(s0,w.z,a0.z); a0.w=fmaf(s0,w.w,a0.w);
                a1.x=fmaf(s1,w.x,a1.x); a1.y=fmaf(s1,w.y,a1.y); a1.z=fmaf(s1,w.z,a1.z); a1.w=fmaf(s1,w.w,a1.w);
                a2.x=fmaf(s2,w.x,a2.x); a2.y=fmaf(s2,w.y,a2.y); a2.z=fmaf(s2,w.z,a2.z); a2.w=fmaf(s2,w.w,a2.w);
                a3.x=fmaf(s3,w.x,a3.x); a3.y=fmaf(s3,w.y,a3.y); a3.z=fmaf(s3,w.z,a3.z); a3.w=fmaf(s3,w.w,a3.w);
            }
            float4* p4 = (float4*)part;
            p4[kg * 128 + 0 * 32 + c4f] = a0; p4[kg * 128 + 1 * 32 + c4f] = a1;
            p4[kg * 128 + 2 * 32 + c4f] = a2; p4[kg * 128 + 3 * 32 + c4f] = a3;
        }
        __syncthreads();
        if (tid < 128) {  // reduce 8 k-partials + bias + residual + LN3 -> out
            const int r = tid >> 5, c4 = tid & 31;
            const float4* p4 = (const float4*)part;
            float4 sum = ((const float4*)p.bf2)[c4];
            #pragma unroll
            for (int kg = 0; kg < 8; ++kg) {
                const float4 v = p4[kg * 128 + r * 32 + c4];
                sum.x += v.x; sum.y += v.y; sum.z += v.z; sum.w += v.w;
            }
            const float4 r4 = ((const float4*)rowS)[r * 32 + c4];
            const float x0 = sum.x + r4.x, x1 = sum.y + r4.y;
            const float x2 = sum.z + r4.z, x3 = sum.w + r4.w;
            float s  = x0 + x1 + x2 + x3;
            float s2 = x0 * x0 + x1 * x1 + x2 * x2 + x3 * x3;
            for (int o = 16; o; o >>= 1) { s += __shfl_xor(s, o, 32); s2 += __shfl_xor(s2, o, 32); }
            const float m = s * (1.f / 128), var = s2 * (1.f / 128) - m * m;
            const float rs = rsqrtf(var + LN_EPS);
            const float4 gv = ((const float4*)p.ln3g)[c4], bv = ((const float4*)p.ln3b)[c4];
            float4 o4;
            o4.x = (x0 - m) * rs * gv.x + bv.x; o4.y = (x1 - m) * rs * gv.y + bv.y;
            o4.z = (x2 - m) * rs * gv.z + bv.z; o4.w = (x3 - m) * rs * gv.w + bv.w;
            ((float4*)p.out)[(size_t)(r0 + r) * 32 + c4] = o4;
        }
    }
}

extern "C" void kernel_launch(void* const* d_in, const int* in_sizes, int n_in,
                              void* d_out, int out_size, void* d_ws, size_t ws_size,
                              hipStream_t stream) {
    (void)in_sizes; (void)n_in; (void)out_size; (void)ws_size;
    P p;
    p.x        = (const float*)d_in[0];
    p.enc      = (const float*)d_in[1];
    p.com_mask = (const float*)d_in[2];
    p.dec_mask = (const float*)d_in[3];
    p.W1q = (const float*)d_in[4];
    p.W1k = (const float*)d_in[5];
    p.b1  = (const float*)d_in[6];
    p.W2  = (const float*)d_in[7];
    // d_in[8] = b2: per-row constant -> dropped (softmax shift invariance)
    p.Ww1 = (const float*)d_in[9];
    p.bw1 = (const float*)d_in[10];
    p.Wd1 = (const float*)d_in[11];
    p.bd1 = (const float*)d_in[12];
    p.Ww2 = (const float*)d_in[13];
    p.bw2 = (const float*)d_in[14];
    p.Wd2 = (const float*)d_in[15];
    p.bd2 = (const float*)d_in[16];
    p.Wf1 = (const float*)d_in[17];
    p.bf1 = (const float*)d_in[18];
    p.Wf2 = (const float*)d_in[19];
    p.bf2 = (const float*)d_in[20];
    p.ln1g = (const float*)d_in[21];
    p.ln1b = (const float*)d_in[22];
    p.ln2g = (const float*)d_in[23];
    p.ln2b = (const float*)d_in[24];
    p.ln3g = (const float*)d_in[25];
    p.ln3b = (const float*)d_in[26];
    p.out  = (float*)d_out;

    float* ws = (float*)d_ws;
    const size_t RD  = (size_t)R * D;      // 131072
    const size_t SSz = (size_t)B * S * S;  // 262144
    p.xw    = ws;
    p.qa    = p.xw    + RD;
    p.kb    = p.qa    + RD;
    p.kv2w  = p.kb    + RD;
    p.kb2   = p.kv2w  + RD;
    p.ka2   = p.kb2   + RD;
    p.qa2   = p.ka2   + RD;
    p.qb2   = p.qa2   + RD;
    p.sbuf  = p.qb2   + RD;    // SSz
    p.sbuf2 = p.sbuf  + SSz;   // SSz
    p.out1  = p.sbuf2 + SSz;

    proj3_kernel<<<dim3(R / 8, 2), 256, 0, stream>>>(p);
    pairwise_self_kernel<<<dim3(8, 8, 4), 256, 0, stream>>>(p);
    attn_tail_kernel<true, true, false><<<R / 4, 256, 0, stream>>>(p);
    pairwise_cross2_kernel<<<dim3(8, 8, 4), 256, 0, stream>>>(p);
    attn_tail_kernel<false, false, true><<<R / 4, 256, 0, stream>>>(p);
}

// Round 9
// 182.726 us; speedup vs baseline: 1.4109x; 1.0042x over previous
//
#include <hip/hip_runtime.h>
#include <math.h>

// DecoderLayer: B=4,N=1,S=256,D=128,H=128,DFF=512, fp32 end-to-end.
// Round-9: 5 dispatches (structural: 5 serial stages, each needs a global
// exchange). Change vs R8: pairwise_cross2 is single-pass — all 4 tiles
// resident in LDS (68KB, >64KB static OK on gfx950, proven R6), one h-loop
// with 8 independent accumulators (96 VALU : 9 LDS-b128 per 4-h vs 48:5),
// 1 barrier instead of 3.
// Grid law (R6/R7): fusion must never drop the grid below 256 blocks.
// R3: grid.sync ~40us on MI355X -> no cooperative path.
//  1. proj3: x -> xw -> {qa,kb} ; enc -> kv2w -> {kb2,ka2}  (chained via LDS)
//  2. pairwise_self (sym term = transpose, read in stage 3)
//  3. attn_tail<SYM,QPROJ>: 4 rows/block x 256: softmax(+sym)+AV(k-split)+
//     outproj(k-split)+res+LN -> out1, then out1 -> q2w -> {qa2,qb2} in LDS
//  4. pairwise_cross2 (both symmetric terms, SINGLE pass)
//  5. attn_tail<FFN>: attention tail -> out2 in LDS -> ffn1+relu+ffn2+res+LN3
// b2 dropped (softmax shift invariance). RES_RATIO=1 -> plain residual add.

#define LN_EPS 1e-6f
#define NEGV  (-1e9f)

constexpr int B = 4, S = 256, D = 128, H = 128, DFF = 512;
constexpr int R = B * S;   // 1024 rows (N=1)
constexpr int LDW = H + 4; // padded pairwise LDS stride (16B-aligned rows)

struct P {
    const float *x, *enc, *com_mask, *dec_mask;
    const float *W1q, *W1k, *b1, *W2;
    const float *Ww1, *bw1, *Wd1, *bd1;
    const float *Ww2, *bw2, *Wd2, *bd2;
    const float *Wf1, *bf1, *Wf2, *bf2;
    const float *ln1g, *ln1b, *ln2g, *ln2b, *ln3g, *ln3b;
    float *out;
    float *xw, *qa, *kb, *kv2w, *kb2, *ka2, *qa2, *qb2;
    float *sbuf, *sbuf2, *out1;
};

// ---- in-LDS 8-row x 128 matmul helper (proj3): row lr, float4-col c4 ----
__device__ __forceinline__ float4 mm8(const float* AshS, const float* W,
                                      const float* bias, int lr, int c4)
{
    const float4* W4 = (const float4*)W;
    float4 acc = bias ? ((const float4*)bias)[c4] : make_float4(0.f, 0.f, 0.f, 0.f);
    #pragma unroll 8
    for (int k = 0; k < 128; ++k) {
        const float a = AshS[lr * 128 + k];
        const float4 w = W4[k * 32 + c4];
        acc.x = fmaf(a, w.x, acc.x); acc.y = fmaf(a, w.y, acc.y);
        acc.z = fmaf(a, w.z, acc.z); acc.w = fmaf(a, w.w, acc.w);
    }
    return acc;
}

// ================= 1: chained projections, grid (R/8, 2) =================
__global__ __launch_bounds__(256) void proj3_kernel(P p)
{
    const int g = blockIdx.y, tid = threadIdx.x;
    const int r0 = blockIdx.x * 8;
    const int lr = tid >> 5, c4 = tid & 31;
    __shared__ float Ash[8 * 128];
    __shared__ float Pw[8 * 128];

    const float* A    = g ? p.enc  : p.x;
    const float* Wp   = g ? p.Ww2  : p.Ww1;
    const float* bp   = g ? p.bw2  : p.bw1;
    float*       o_w  = g ? p.kv2w : p.xw;
    const float* Wsec = g ? p.W1k  : p.W1q;  // kb2 | qa
    const float* bsec = g ? nullptr: p.b1;
    float*       o_s  = g ? p.kb2  : p.qa;
    const float* Wthr = g ? p.W1q  : p.W1k;  // ka2 | kb
    float*       o_t  = g ? p.ka2  : p.kb;

    ((float4*)Ash)[tid] = ((const float4*)(A + (size_t)r0 * 128))[tid];
    __syncthreads();
    {
        const float4 w = mm8(Ash, Wp, bp, lr, c4);
        ((float4*)(Pw + lr * 128))[c4] = w;
        ((float4*)o_w)[(size_t)(r0 + lr) * 32 + c4] = w;
    }
    __syncthreads();
    {
        const float4 q = mm8(Pw, Wsec, bsec, lr, c4);
        ((float4*)o_s)[(size_t)(r0 + lr) * 32 + c4] = q;
        const float4 k = mm8(Pw, Wthr, nullptr, lr, c4);
        ((float4*)o_t)[(size_t)(r0 + lr) * 32 + c4] = k;
    }
}

// ---- pairwise accumulate helper (float4 over h), parameterized accs ----
#define PW_STEP_N(AP0, AP1, BP0, BP1, A00, A01, A10, A11)                      \
    {                                                                          \
        const float4 w  = *(const float4*)(W2s + h);                           \
        const float4 a0 = *(const float4*)((AP0) + h);                         \
        const float4 a1 = *(const float4*)((AP1) + h);                         \
        const float4 b0 = *(const float4*)((BP0) + h);                         \
        const float4 b1 = *(const float4*)((BP1) + h);                         \
        A00 = fmaf(fmaxf(a0.x+b0.x,0.f),w.x,A00); A00 = fmaf(fmaxf(a0.y+b0.y,0.f),w.y,A00); \
        A00 = fmaf(fmaxf(a0.z+b0.z,0.f),w.z,A00); A00 = fmaf(fmaxf(a0.w+b0.w,0.f),w.w,A00); \
        A01 = fmaf(fmaxf(a0.x+b1.x,0.f),w.x,A01); A01 = fmaf(fmaxf(a0.y+b1.y,0.f),w.y,A01); \
        A01 = fmaf(fmaxf(a0.z+b1.z,0.f),w.z,A01); A01 = fmaf(fmaxf(a0.w+b1.w,0.f),w.w,A01); \
        A10 = fmaf(fmaxf(a1.x+b0.x,0.f),w.x,A10); A10 = fmaf(fmaxf(a1.y+b0.y,0.f),w.y,A10); \
        A10 = fmaf(fmaxf(a1.z+b0.z,0.f),w.z,A10); A10 = fmaf(fmaxf(a1.w+b0.w,0.f),w.w,A10); \
        A11 = fmaf(fmaxf(a1.x+b1.x,0.f),w.x,A11); A11 = fmaf(fmaxf(a1.y+b1.y,0.f),w.y,A11); \
        A11 = fmaf(fmaxf(a1.z+b1.z,0.f),w.z,A11); A11 = fmaf(fmaxf(a1.w+b1.w,0.f),w.w,A11); \
    }

// ================= 2: self pairwise (single term) =================
__global__ __launch_bounds__(256) void pairwise_self_kernel(P p)
{
    __shared__ __align__(16) float As[32 * LDW];
    __shared__ __align__(16) float Bs[32 * LDW];
    __shared__ __align__(16) float W2s[H];
    const int b = blockIdx.z, q0 = blockIdx.y * 32, k0 = blockIdx.x * 32;
    const int tid = threadIdx.x, bS = b * S;
    for (int i = tid; i < 32 * (H / 4); i += 256) {
        const int r = i >> 5, c4 = i & 31;
        ((float4*)(As + r * LDW))[c4] = ((const float4*)(p.qa + (size_t)(bS + q0 + r) * H))[c4];
        ((float4*)(Bs + r * LDW))[c4] = ((const float4*)(p.kb + (size_t)(bS + k0 + r) * H))[c4];
    }
    if (tid < H / 4) ((float4*)W2s)[tid] = ((const float4*)p.W2)[tid];
    __syncthreads();
    const int tx = tid & 15, ty = tid >> 4;
    const float* A0 = As + (2 * ty) * LDW; const float* A1 = A0 + LDW;
    const float* B0 = Bs + (2 * tx) * LDW; const float* B1 = B0 + LDW;
    float acc00 = 0.f, acc01 = 0.f, acc10 = 0.f, acc11 = 0.f;
    #pragma unroll 4
    for (int h = 0; h < H; h += 4)
        PW_STEP_N(A0, A1, B0, B1, acc00, acc01, acc10, acc11);
    const size_t base = (size_t)(bS + q0 + 2 * ty) * S + (k0 + 2 * tx);
    *(float2*)(p.sbuf + base)     = make_float2(acc00, acc01);
    *(float2*)(p.sbuf + base + S) = make_float2(acc10, acc11);
}

// ===== 4: cross pairwise, both symmetric terms, SINGLE pass =====
// 4 tiles resident (68.1 KB LDS); one h-loop, 8 independent accumulators.
__global__ __launch_bounds__(256) void pairwise_cross2_kernel(P p)
{
    __shared__ __align__(16) float As1[32 * LDW];
    __shared__ __align__(16) float Bs1[32 * LDW];
    __shared__ __align__(16) float As2[32 * LDW];
    __shared__ __align__(16) float Bs2[32 * LDW];
    __shared__ __align__(16) float W2s[H];
    const int b = blockIdx.z, q0 = blockIdx.y * 32, k0 = blockIdx.x * 32;
    const int tid = threadIdx.x, bS = b * S;

    for (int i = tid; i < 32 * (H / 4); i += 256) {
        const int r = i >> 5, c4 = i & 31;
        ((float4*)(As1 + r * LDW))[c4] = ((const float4*)(p.qa2 + (size_t)(bS + q0 + r) * H))[c4];
        ((float4*)(Bs1 + r * LDW))[c4] = ((const float4*)(p.kb2 + (size_t)(bS + k0 + r) * H))[c4];
        ((float4*)(As2 + r * LDW))[c4] = ((const float4*)(p.qb2 + (size_t)(bS + q0 + r) * H))[c4];
        ((float4*)(Bs2 + r * LDW))[c4] = ((const float4*)(p.ka2 + (size_t)(bS + k0 + r) * H))[c4];
    }
    if (tid < H / 4) ((float4*)W2s)[tid] = ((const float4*)p.W2)[tid];
    __syncthreads();

    const int tx = tid & 15, ty = tid >> 4;
    const float* A0 = As1 + (2 * ty) * LDW; const float* A1 = A0 + LDW;
    const float* B0 = Bs1 + (2 * tx) * LDW; const float* B1 = B0 + LDW;
    const float* C0 = As2 + (2 * ty) * LDW; const float* C1 = C0 + LDW;
    const float* D0 = Bs2 + (2 * tx) * LDW; const float* D1 = D0 + LDW;
    float a00 = 0.f, a01 = 0.f, a10 = 0.f, a11 = 0.f;
    float b00 = 0.f, b01 = 0.f, b10 = 0.f, b11 = 0.f;
    #pragma unroll 4
    for (int h = 0; h < H; h += 4) {
        PW_STEP_N(A0, A1, B0, B1, a00, a01, a10, a11);
        PW_STEP_N(C0, C1, D0, D1, b00, b01, b10, b11);
    }
    const size_t base = (size_t)(bS + q0 + 2 * ty) * S + (k0 + 2 * tx);
    *(float2*)(p.sbuf2 + base)     = make_float2(a00 + b00, a01 + b01);
    *(float2*)(p.sbuf2 + base + S) = make_float2(a10 + b10, a11 + b11);
}

// ======= 3/5: 4-row attn tail: softmax(+sym)+AV+outproj+res+LN =======
// grid = R/4 = 256 blocks (full machine). 256 threads = 4 waves; wave r owns
// row r. k-split partials through LDS keep per-thread chains short.
// smem carve (floats): rowS [0,512) | s8 [512,1536) | avp [1536,2560) |
//   aoS [2560,3072) | pp [3072,4096)
// QPROJ aliases: qpp = s8, q2wS = avp.
// FFN aliases (all attn scratch dead): hidP [512,4608) | part [4608,8704)
template<bool SYM, bool QPROJ, bool FFN>
__global__ __launch_bounds__(256) void attn_tail_kernel(P p)
{
    __shared__ __align__(16) float smem[FFN ? 8704 : 4096];
    float* rowS = smem;
    float* s8   = smem + 512;
    float* avp  = smem + 1536;
    float* aoS  = smem + 2560;
    float* pp   = smem + 3072;

    const float* Sin  = SYM ? p.sbuf : p.sbuf2;
    const float* mask = SYM ? p.com_mask : p.dec_mask;
    const float* V    = SYM ? p.xw : p.kv2w;
    const float* Wd   = SYM ? p.Wd1 : p.Wd2;
    const float* bd   = SYM ? p.bd1 : p.bd2;
    const float* res  = SYM ? p.x : p.out1;
    const float* lg   = SYM ? p.ln1g : p.ln2g;
    const float* lb   = SYM ? p.ln1b : p.ln2b;

    const int tid = threadIdx.x;
    const int r0 = blockIdx.x * 4, b = r0 >> 8, bS = b * S;

    // ---- scores + mask (+sym transpose) into s8[4][256] ----
    for (int i = tid; i < 4 * 256; i += 256) {
        const int r = i >> 8, k = i & 255;
        const int row = r0 + r, q = row & 255;
        float l = Sin[(size_t)row * S + k];
        if (SYM) l += Sin[(size_t)(bS + k) * S + q];
        l += mask[(size_t)row * S + k] * NEGV;
        s8[i] = l;
    }
    __syncthreads();

    // ---- softmax: wave g owns row g; 64-lane shuffles ----
    {
        const int g = tid >> 6, c = tid & 63;
        float* rowp = s8 + g * 256;
        float m = -INFINITY;
        #pragma unroll
        for (int k = c; k < 256; k += 64) m = fmaxf(m, rowp[k]);
        for (int o = 32; o; o >>= 1) m = fmaxf(m, __shfl_xor(m, o, 64));
        float s = 0.f;
        #pragma unroll
        for (int k = c; k < 256; k += 64) { const float e = __expf(rowp[k] - m); rowp[k] = e; s += e; }
        for (int o = 32; o; o >>= 1) s += __shfl_xor(s, o, 64);
        const float rinv = 1.f / s;
        #pragma unroll
        for (int k = c; k < 256; k += 64) rowp[k] *= rinv;
    }
    __syncthreads();

    // ---- AV, k-split by 2: wave r, half-wave kh ----
    {
        const int r = tid >> 6, t = tid & 63, c4 = t & 31, kh = t >> 5;
        const float4* V4 = (const float4*)(V + (size_t)bS * D);
        const float* sp = s8 + r * 256 + kh * 128;
        float4 acc = make_float4(0.f, 0.f, 0.f, 0.f);
        #pragma unroll 8
        for (int k = 0; k < 128; ++k) {
            const float a = sp[k];
            const float4 v = V4[(kh * 128 + k) * 32 + c4];
            acc.x = fmaf(a, v.x, acc.x); acc.y = fmaf(a, v.y, acc.y);
            acc.z = fmaf(a, v.z, acc.z); acc.w = fmaf(a, v.w, acc.w);
        }
        ((float4*)avp)[(r * 2 + kh) * 32 + c4] = acc;
    }
    __syncthreads();
    if (tid < 128) {
        const int r = tid >> 5, c4 = tid & 31;
        const float4 a = ((const float4*)avp)[(r * 2 + 0) * 32 + c4];
        const float4 bq = ((const float4*)avp)[(r * 2 + 1) * 32 + c4];
        ((float4*)aoS)[r * 32 + c4] = make_float4(a.x + bq.x, a.y + bq.y, a.z + bq.z, a.w + bq.w);
    }
    __syncthreads();

    // ---- outproj, k-split by 2 ----
    {
        const int kh = tid >> 7, unit = tid & 127, r = unit >> 5, c4 = unit & 31;
        const float4* W4 = (const float4*)Wd;
        const float* ap = aoS + r * 128 + kh * 64;
        float4 acc = make_float4(0.f, 0.f, 0.f, 0.f);
        #pragma unroll 8
        for (int k = 0; k < 64; ++k) {
            const float a = ap[k];
            const float4 w = W4[(kh * 64 + k) * 32 + c4];
            acc.x = fmaf(a, w.x, acc.x); acc.y = fmaf(a, w.y, acc.y);
            acc.z = fmaf(a, w.z, acc.z); acc.w = fmaf(a, w.w, acc.w);
        }
        ((float4*)pp)[kh * 128 + unit] = acc;
    }
    __syncthreads();

    // ---- combine + bias + residual + LN -> rowS (and out1 if SYM) ----
    if (tid < 128) {
        const int r = tid >> 5, c4 = tid & 31;
        const float4 p0 = ((const float4*)pp)[tid];
        const float4 p1 = ((const float4*)pp)[128 + tid];
        const float4 bv0 = ((const float4*)bd)[c4];
        const float4 r4 = ((const float4*)(res + (size_t)(r0 + r) * 128))[c4];
        const float x0 = p0.x + p1.x + bv0.x + r4.x;
        const float x1 = p0.y + p1.y + bv0.y + r4.y;
        const float x2 = p0.z + p1.z + bv0.z + r4.z;
        const float x3 = p0.w + p1.w + bv0.w + r4.w;
        float s  = x0 + x1 + x2 + x3;
        float s2 = x0 * x0 + x1 * x1 + x2 * x2 + x3 * x3;
        for (int o = 16; o; o >>= 1) { s += __shfl_xor(s, o, 32); s2 += __shfl_xor(s2, o, 32); }
        const float m = s * (1.f / 128), var = s2 * (1.f / 128) - m * m;
        const float rs = rsqrtf(var + LN_EPS);
        const float4 gv = ((const float4*)lg)[c4], bv = ((const float4*)lb)[c4];
        float4 o4;
        o4.x = (x0 - m) * rs * gv.x + bv.x; o4.y = (x1 - m) * rs * gv.y + bv.y;
        o4.z = (x2 - m) * rs * gv.z + bv.z; o4.w = (x3 - m) * rs * gv.w + bv.w;
        ((float4*)rowS)[r * 32 + c4] = o4;
        if (SYM) ((float4*)p.out1)[(size_t)(r0 + r) * 32 + c4] = o4;
    }
    __syncthreads();

    if (QPROJ) {
        float* qpp  = s8;   // [2][512]
        float* q2wS = avp;  // [4][128]
        {   // q2w partials, k-split by 2
            const int kh = tid >> 7, unit = tid & 127, r = unit >> 5, c4 = unit & 31;
            const float4* W4 = (const float4*)p.Ww2;
            const float* ap = rowS + r * 128 + kh * 64;
            float4 acc = make_float4(0.f, 0.f, 0.f, 0.f);
            #pragma unroll 8
            for (int k = 0; k < 64; ++k) {
                const float a = ap[k];
                const float4 w = W4[(kh * 64 + k) * 32 + c4];
                acc.x = fmaf(a, w.x, acc.x); acc.y = fmaf(a, w.y, acc.y);
                acc.z = fmaf(a, w.z, acc.z); acc.w = fmaf(a, w.w, acc.w);
            }
            ((float4*)qpp)[kh * 128 + unit] = acc;
        }
        __syncthreads();
        if (tid < 128) {
            const int c4 = tid & 31;
            const float4 p0 = ((const float4*)qpp)[tid];
            const float4 p1 = ((const float4*)qpp)[128 + tid];
            const float4 bw = ((const float4*)p.bw2)[c4];
            ((float4*)q2wS)[tid] = make_float4(p0.x + p1.x + bw.x, p0.y + p1.y + bw.y,
                                               p0.z + p1.z + bw.z, p0.w + p1.w + bw.w);
        }
        __syncthreads();
        {   // qa2 = q2w@W1q + b1 ; qb2 = q2w@W1k + b1  (256 units exactly)
            const int which = tid >> 7, unit = tid & 127, r = unit >> 5, c4 = unit & 31;
            const float4* W4 = (const float4*)(which ? p.W1k : p.W1q);
            float* oq = which ? p.qb2 : p.qa2;
            const float* ap = q2wS + r * 128;
            float4 acc = ((const float4*)p.b1)[c4];
            #pragma unroll 8
            for (int k = 0; k < 128; ++k) {
                const float a = ap[k];
                const float4 w = W4[k * 32 + c4];
                acc.x = fmaf(a, w.x, acc.x); acc.y = fmaf(a, w.y, acc.y);
                acc.z = fmaf(a, w.z, acc.z); acc.w = fmaf(a, w.w, acc.w);
            }
            ((float4*)oq)[(size_t)(r0 + r) * 32 + c4] = acc;
        }
    }

    if (FFN) {
        float* hidP = smem + 512;   // [2][4][512] partials; [0,2048) becomes hidden
        float* part = smem + 4608;  // [8][4][128]
        {   // ffn1: float4-col c of 128, k-half kh; 4-row register accs
            const int c = tid & 127, kh = tid >> 7;
            const float4* Wf1_4 = (const float4*)p.Wf1;
            float4 a0 = make_float4(0.f,0.f,0.f,0.f), a1 = a0, a2 = a0, a3 = a0;
            const int kbase = kh * 64;
            #pragma unroll 8
            for (int k = 0; k < 64; ++k) {
                const int kk = kbase + k;
                const float4 w = Wf1_4[kk * 128 + c];
                const float s0 = rowS[kk],       s1 = rowS[128 + kk];
                const float s2 = rowS[256 + kk], s3 = rowS[384 + kk];
                a0.x=fmaf(s0,w.x,a0.x); a0.y=fmaf(s0,w.y,a0.y); a0.z=fmaf(s0,w.z,a0.z); a0.w=fmaf(s0,w.w,a0.w);
                a1.x=fmaf(s1,w.x,a1.x); a1.y=fmaf(s1,w.y,a1.y); a1.z=fmaf(s1,w.z,a1.z); a1.w=fmaf(s1,w.w,a1.w);
                a2.x=fmaf(s2,w.x,a2.x); a2.y=fmaf(s2,w.y,a2.y); a2.z=fmaf(s2,w.z,a2.z); a2.w=fmaf(s2,w.w,a2.w);
                a3.x=fmaf(s3,w.x,a3.x); a3.y=fmaf(s3,w.y,a3.y); a3.z=fmaf(s3,w.z,a3.z); a3.w=fmaf(s3,w.w,a3.w);
            }
            float4* h4 = (float4*)hidP;
            const int base = kh * 512;
            h4[base + 0*128 + c] = a0; h4[base + 1*128 + c] = a1;
            h4[base + 2*128 + c] = a2; h4[base + 3*128 + c] = a3;
        }
        __syncthreads();
        for (int i = tid; i < 2048; i += 256) {
            hidP[i] = fmaxf(hidP[i] + hidP[2048 + i] + p.bf1[i & 511], 0.f);
        }
        __syncthreads();
        {   // ffn2: c4f of 32, k-group kg (8 x 64); 4-row register accs
            const int c4f = tid & 31, kg = tid >> 5;
            const float4* Wf2_4 = (const float4*)p.Wf2;
            float4 a0 = make_float4(0.f,0.f,0.f,0.f), a1 = a0, a2 = a0, a3 = a0;
            const int kbase = kg * 64;
            const float* h0 = hidP + 0 * 512 + kbase;
            const float* h1 = hidP + 1 * 512 + kbase;
            const float* h2 = hidP + 2 * 512 + kbase;
            const float* h3 = hidP + 3 * 512 + kbase;
            #pragma unroll 8
            for (int k = 0; k < 64; ++k) {
                const float4 w = Wf2_4[(kbase + k) * 32 + c4f];
                const float s0 = h0[k], s1 = h1[k], s2 = h2[k], s3 = h3[k];
                a0.x=fmaf(s0,w.x,a0.x); a0.y=fmaf(s0,w.y,a0.y); a0.z=fmaf(s0,w.z,a0.z); a0.w=fmaf(s0,w.w,a0.w);
                a1.x=fmaf(s1,w.x,a1.x); a1.y=fmaf(s1,w.y,a1.y); a1.z=fmaf(s1,w.z,a1.z); a1.w=fmaf(s1,w.w,a1.w);
                a2.x=fmaf(s2,w.x,a2.x); a2.y=fmaf(s2,w.y,a2.y); a2.z=fmaf(s2,w.z,a2.z); a2.w=fmaf(s2,w.w,a2.w);
                a3.x=fmaf(s3,w.x,a3.x); a3.y=fmaf(s3,w.y,a3.y); a3.z=fmaf(s3,w.z,a3.z); a3.w=fmaf(s3,w.w,a3.w);
            }
            float4* p4 = (float4*)part;
            p4[kg * 128 + 0 * 32 + c4f] = a0; p4[kg * 128 + 1 * 32 + c4f] = a1;
            p4[kg * 128 + 2 * 32 + c4f] = a2; p4[kg * 128 + 3 * 32 + c4f] = a3;
        }
        __syncthreads();
        if (tid < 128) {  // reduce 8 k-partials + bias + residual + LN3 -> out
            const int r = tid >> 5, c4 = tid & 31;
            const float4* p4 = (const float4*)part;
            float4 sum = ((const float4*)p.bf2)[c4];
            #pragma unroll
            for (int kg = 0; kg < 8; ++kg) {
                const float4 v = p4[kg * 128 + r * 32 + c4];
                sum.x += v.x; sum.y += v.y; sum.z += v.z; sum.w += v.w;
            }
            const float4 r4 = ((const float4*)rowS)[r * 32 + c4];
            const float x0 = sum.x + r4.x, x1 = sum.y + r4.y;
            const float x2 = sum.z + r4.z, x3 = sum.w + r4.w;
            float s  = x0 + x1 + x2 + x3;
            float s2 = x0 * x0 + x1 * x1 + x2 * x2 + x3 * x3;
            for (int o = 16; o; o >>= 1) { s += __shfl_xor(s, o, 32); s2 += __shfl_xor(s2, o, 32); }
            const float m = s * (1.f / 128), var = s2 * (1.f / 128) - m * m;
            const float rs = rsqrtf(var + LN_EPS);
            const float4 gv = ((const float4*)p.ln3g)[c4], bv = ((const float4*)p.ln3b)[c4];
            float4 o4;
            o4.x = (x0 - m) * rs * gv.x + bv.x; o4.y = (x1 - m) * rs * gv.y + bv.y;
            o4.z = (x2 - m) * rs * gv.z + bv.z; o4.w = (x3 - m) * rs * gv.w + bv.w;
            ((float4*)p.out)[(size_t)(r0 + r) * 32 + c4] = o4;
        }
    }
}

extern "C" void kernel_launch(void* const* d_in, const int* in_sizes, int n_in,
                              void* d_out, int out_size, void* d_ws, size_t ws_size,
                              hipStream_t stream) {
    (void)in_sizes; (void)n_in; (void)out_size; (void)ws_size;
    P p;
    p.x        = (const float*)d_in[0];
    p.enc      = (const float*)d_in[1];
    p.com_mask = (const float*)d_in[2];
    p.dec_mask = (const float*)d_in[3];
    p.W1q = (const float*)d_in[4];
    p.W1k = (const float*)d_in[5];
    p.b1  = (const float*)d_in[6];
    p.W2  = (const float*)d_in[7];
    // d_in[8] = b2: per-row constant -> dropped (softmax shift invariance)
    p.Ww1 = (const float*)d_in[9];
    p.bw1 = (const float*)d_in[10];
    p.Wd1 = (const float*)d_in[11];
    p.bd1 = (const float*)d_in[12];
    p.Ww2 = (const float*)d_in[13];
    p.bw2 = (const float*)d_in[14];
    p.Wd2 = (const float*)d_in[15];
    p.bd2 = (const float*)d_in[16];
    p.Wf1 = (const float*)d_in[17];
    p.bf1 = (const float*)d_in[18];
    p.Wf2 = (const float*)d_in[19];
    p.bf2 = (const float*)d_in[20];
    p.ln1g = (const float*)d_in[21];
    p.ln1b = (const float*)d_in[22];
    p.ln2g = (const float*)d_in[23];
    p.ln2b = (const float*)d_in[24];
    p.ln3g = (const float*)d_in[25];
    p.ln3b = (const float*)d_in[26];
    p.out  = (float*)d_out;

    float* ws = (float*)d_ws;
    const size_t RD  = (size_t)R * D;      // 131072
    const size_t SSz = (size_t)B * S * S;  // 262144
    p.xw    = ws;
    p.qa    = p.xw    + RD;
    p.kb    = p.qa    + RD;
    p.kv2w  = p.kb    + RD;
    p.kb2   = p.kv2w  + RD;
    p.ka2   = p.kb2   + RD;
    p.qa2   = p.ka2   + RD;
    p.qb2   = p.qa2   + RD;
    p.sbuf  = p.qb2   + RD;    // SSz
    p.sbuf2 = p.sbuf  + SSz;   // SSz
    p.out1  = p.sbuf2 + SSz;

    proj3_kernel<<<dim3(R / 8, 2), 256, 0, stream>>>(p);
    pairwise_self_kernel<<<dim3(8, 8, 4), 256, 0, stream>>>(p);
    attn_tail_kernel<true, true, false><<<R / 4, 256, 0, stream>>>(p);
    pairwise_cross2_kernel<<<dim3(8, 8, 4), 256, 0, stream>>>(p);
    attn_tail_kernel<false, false, true><<<R / 4, 256, 0, stream>>>(p);
}